// Round 1
// baseline (645.153 us; speedup 1.0000x reference)
//
#include <hip/hip_runtime.h>
#include <hip/hip_bf16.h>
#include <math.h>

#define BATCH 16
#define H 1024
#define W 1024
#define TS 64          // tile size for NMS
#define R 7            // NMS radius (15x15 window)
#define HALO (TS + 2*R)   // 78
#define HALO_PAD 80
#define CAP 4096       // candidate capacity per image (expected ~2330)
#define TOPK 2048

struct WS {
  double term1[BATCH];          // sum(score1^2 * mask) per image
  double corr[BATCH];           // sum over stamps of (w^2 - 2*s1*w)*mask
  unsigned int masksum[BATCH];  // count of mask pixels per image
  int cand_count[BATCH];
  int keycount[BATCH];
  int pad[3];
  float cand_val[BATCH * CAP];
  int   cand_idx[BATCH * CAP];
  int   keys[BATCH * TOPK];
};

// Normalized 1-D Gaussian, ks=7 sigma=1 (matches JAX f32 computation to ~1 ulp)
__constant__ float GW[7] = {
  0.004433048175f, 0.054005582623f, 0.242036229376f, 0.399050279652f,
  0.242036229376f, 0.054005582623f, 0.004433048175f
};

__global__ void k_zero(WS* ws) {
  int t = threadIdx.x;
  if (t < BATCH) {
    ws->term1[t] = 0.0;
    ws->corr[t] = 0.0;
    ws->masksum[t] = 0u;
    ws->cand_count[t] = 0;
    ws->keycount[t] = 0;
  }
}

// One block per 64x64 tile: NMS candidate extraction + dense term accumulation.
__global__ __launch_bounds__(256) void k_nms(const float* __restrict__ score1,
                                             const float* __restrict__ score2,
                                             const int* __restrict__ mask,
                                             WS* __restrict__ ws) {
  const int blk = blockIdx.x;
  const int b = blk >> 8;             // 256 tiles per image
  const int tile = blk & 255;
  const int ty0 = (tile >> 4) << 6;
  const int tx0 = (tile & 15) << 6;
  const int tid = threadIdx.x;
  const size_t ibase = (size_t)b * (H * W);

  __shared__ float halo[HALO][HALO_PAD];
  __shared__ float rmax[HALO][TS];

  // load score2 halo tile (OOB = -inf, matching reduce_window init)
  for (int i = tid; i < HALO * HALO; i += 256) {
    int ly = i / HALO, lx = i - ly * HALO;
    int gy = ty0 - R + ly, gx = tx0 - R + lx;
    float v = -INFINITY;
    if (gy >= 0 && gy < H && gx >= 0 && gx < W)
      v = score2[ibase + (size_t)gy * W + gx];
    halo[ly][lx] = v;
  }

  // dense pass: sum score1^2*mask and mask count for this tile; cache mask bits
  float t1 = 0.f; int mcnt = 0; unsigned int mbits = 0;
  for (int k = 0; k < 16; k++) {
    int p = tid + k * 256;
    int y = p >> 6, x = p & 63;
    size_t gi = ibase + (size_t)(ty0 + y) * W + (tx0 + x);
    int m = mask[gi];
    float s1 = score1[gi];
    if (m) { t1 += s1 * s1; mcnt++; mbits |= (1u << k); }
  }
  __syncthreads();

  // horizontal 15-max
  for (int i = tid; i < HALO * TS; i += 256) {
    int ly = i >> 6, x = i & 63;
    float m = halo[ly][x];
    #pragma unroll
    for (int d = 1; d < 15; d++) m = fmaxf(m, halo[ly][x + d]);
    rmax[ly][x] = m;
  }
  __syncthreads();

  // vertical 15-max + candidate emit
  for (int k = 0; k < 16; k++) {
    int p = tid + k * 256;
    int y = p >> 6, x = p & 63;
    float s = halo[y + R][x + R];
    float pm = rmax[y][x];
    #pragma unroll
    for (int d = 1; d < 15; d++) pm = fmaxf(pm, rmax[y + d][x]);
    if (s == pm && ((mbits >> k) & 1u) && s > 0.f) {
      int slot = atomicAdd(&ws->cand_count[b], 1);
      if (slot < CAP) {
        ws->cand_val[b * CAP + slot] = s;
        ws->cand_idx[b * CAP + slot] = (ty0 + y) * W + (tx0 + x);
      }
    }
  }

  // block reduce t1 / mcnt
  __shared__ float rf[256];
  __shared__ int ri[256];
  rf[tid] = t1; ri[tid] = mcnt;
  __syncthreads();
  for (int s2 = 128; s2 > 0; s2 >>= 1) {
    if (tid < s2) { rf[tid] += rf[tid + s2]; ri[tid] += ri[tid + s2]; }
    __syncthreads();
  }
  if (tid == 0) {
    atomicAdd(&ws->term1[b], (double)rf[0]);
    atomicAdd(&ws->masksum[b], (unsigned int)ri[0]);
  }
}

// Exact top-k selection by rank; replicates lax.top_k tie-breaking (lower idx wins).
__global__ __launch_bounds__(1024) void k_topk(WS* __restrict__ ws) {
  const int b = blockIdx.x >> 2;
  const int slice = blockIdx.x & 3;
  int n = ws->cand_count[b]; if (n > CAP) n = CAP;
  const int nPad = (n + 3) & ~3;
  __shared__ __align__(16) float sval[CAP];
  __shared__ int sidx[CAP];
  const int tid = threadIdx.x;
  for (int j = tid; j < nPad; j += 1024) {
    sval[j] = (j < n) ? ws->cand_val[b * CAP + j] : -1.f;
    sidx[j] = (j < n) ? ws->cand_idx[b * CAP + j] : -1;
  }
  __syncthreads();
  const int i = slice * 1024 + tid;
  if (i >= n) return;
  const float vi = sval[i];
  const int xi = sidx[i];
  int rank = 0;
  for (int j = 0; j < nPad; j += 4) {
    float4 v = *(const float4*)&sval[j];
    rank += (v.x > vi) + (v.y > vi) + (v.z > vi) + (v.w > vi);
    if (v.x == vi && sidx[j + 0] < xi) rank++;
    if (v.y == vi && sidx[j + 1] < xi) rank++;
    if (v.z == vi && sidx[j + 2] < xi) rank++;
    if (v.w == vi && sidx[j + 3] < xi) rank++;
  }
  if (rank < TOPK) {
    int pos = atomicAdd(&ws->keycount[b], 1);
    if (pos < TOPK) ws->keys[b * TOPK + pos] = xi;
  }
}

// One 64-lane wave per keypoint; 49 lanes cover the 7x7 Gaussian stamp.
__global__ __launch_bounds__(256) void k_stamp(const float* __restrict__ score1,
                                               const int* __restrict__ mask,
                                               WS* __restrict__ ws) {
  const int blk = blockIdx.x;
  const int b = blk >> 9;              // 512 blocks per image (4 keys each)
  const int k0 = (blk & 511) * 4;
  const int wave = threadIdx.x >> 6;
  const int lane = threadIdx.x & 63;
  const int k = k0 + wave;
  int nkeys = ws->keycount[b]; if (nkeys > TOPK) nkeys = TOPK;
  float contrib = 0.f;
  if (k < nkeys && lane < 49) {
    int c = ws->keys[b * TOPK + k];
    int cy = c >> 10, cx = c & 1023;
    int dy = lane / 7 - 3, dx = lane % 7 - 3;
    int py = cy + dy, px = cx + dx;
    if (py >= 0 && py < H && px >= 0 && px < W) {
      size_t gi = (size_t)b * (H * W) + (size_t)py * W + px;
      if (mask[gi]) {
        float w = GW[dy + 3] * GW[dx + 3];
        float s1 = score1[gi];
        contrib = w * w - 2.f * s1 * w;
      }
    }
  }
  for (int off = 32; off > 0; off >>= 1) contrib += __shfl_down(contrib, off);
  __shared__ float wr[4];
  if (lane == 0) wr[wave] = contrib;
  __syncthreads();
  if (threadIdx.x == 0) {
    float sum = wr[0] + wr[1] + wr[2] + wr[3];
    atomicAdd(&ws->corr[b], (double)sum);
  }
}

__global__ void k_final(WS* __restrict__ ws, float* __restrict__ out) {
  if (threadIdx.x == 0 && blockIdx.x == 0) {
    double acc = 0.0;
    for (int b = 0; b < BATCH; b++) {
      double denom = (double)ws->masksum[b];
      if (denom < 1e-8) denom = 1e-8;
      acc += (ws->term1[b] + ws->corr[b]) / denom;
    }
    out[0] = (float)(acc / BATCH);
  }
}

extern "C" void kernel_launch(void* const* d_in, const int* in_sizes, int n_in,
                              void* d_out, int out_size, void* d_ws, size_t ws_size,
                              hipStream_t stream) {
  const float* score1 = (const float*)d_in[0];
  const float* score2 = (const float*)d_in[1];
  const int*   mask   = (const int*)d_in[2];
  float* out = (float*)d_out;
  WS* ws = (WS*)d_ws;

  k_zero<<<1, 64, 0, stream>>>(ws);
  k_nms<<<BATCH * 256, 256, 0, stream>>>(score1, score2, mask, ws);
  k_topk<<<BATCH * 4, 1024, 0, stream>>>(ws);
  k_stamp<<<BATCH * (TOPK / 4), 256, 0, stream>>>(score1, mask, ws);
  k_final<<<1, 1, 0, stream>>>(ws, out);
}

// Round 2
// 537.412 us; speedup vs baseline: 1.2005x; 1.2005x over previous
//
#include <hip/hip_runtime.h>
#include <math.h>

#define BATCH 16
#define H 1024
#define W 1024
#define TS 64
#define HROWS 78      // 64 + 2*7 halo rows
#define CGW 20        // float4 groups per halo row (80 floats: cols tx0-8 .. tx0+71)
#define CGP 21        // padded row stride in float4 (336B: breaks 128B bank aliasing)
#define CAP 4096
#define TOPK 2048

struct WS {
  double term1[BATCH];          // sum(score1^2 * mask)
  double corr[BATCH];           // sum over stamps of (w^2 - 2*s1*w)*mask
  unsigned int masksum[BATCH];
  int cand_count[BATCH];
  float cand_val[BATCH * CAP];
  int   cand_idx[BATCH * CAP];
};

// Normalized 1-D Gaussian, ks=7 sigma=1 (matches JAX f32; validated absmax 0.0 in R1)
__constant__ float GW[7] = {
  0.004433048175f, 0.054005582623f, 0.242036229376f, 0.399050279652f,
  0.242036229376f, 0.054005582623f, 0.004433048175f
};

__device__ __forceinline__ float4 max4(float4 a, float4 b) {
  float4 r;
  r.x = fmaxf(a.x, b.x); r.y = fmaxf(a.y, b.y);
  r.z = fmaxf(a.z, b.z); r.w = fmaxf(a.w, b.w);
  return r;
}

__global__ void k_zero(WS* ws) {
  int t = threadIdx.x;
  if (t < BATCH) {
    ws->term1[t] = 0.0;
    ws->corr[t] = 0.0;
    ws->masksum[t] = 0u;
    ws->cand_count[t] = 0;
  }
}

// One block per 64x64 tile. Phase 1: float4 halo load. Phase 2: vertical 15-max
// (prefix/suffix tree, 8 rows/thread). Phase 3: horizontal 15-max in registers +
// candidate emit + dense term, all from float4 accesses.
__global__ __launch_bounds__(256) void k_nms(const float* __restrict__ score1,
                                             const float* __restrict__ score2,
                                             const int* __restrict__ mask,
                                             WS* __restrict__ ws) {
  const int blk = blockIdx.x;
  const int b = blk >> 8;
  const int tile = blk & 255;
  const int ty0 = (tile >> 4) << 6;
  const int tx0 = (tile & 15) << 6;
  const int tid = threadIdx.x;
  const size_t ibase = (size_t)b * ((size_t)H * W);

  __shared__ float4 halo[HROWS][CGP];   // halo[r][c] ~ global (ty0-7+r, tx0-8+4c)
  __shared__ float4 rmax[TS][CGP];      // vertical 15-max, output rows 0..63
  __shared__ float wsumf[4];
  __shared__ int   wsumi[4];

  // ---- phase 1: load score2 halo as float4 ----
  const bool interior = (ty0 >= 7) && (ty0 + 70 < H) && (tx0 >= 8) && (tx0 + 71 < W);
  if (interior) {
    for (int i = tid; i < HROWS * CGW; i += 256) {
      int r = i / CGW, c = i - r * CGW;
      const float4* p = (const float4*)(score2 + ibase + (size_t)(ty0 - 7 + r) * W + (tx0 - 8)) + c;
      halo[r][c] = *p;
    }
  } else {
    for (int i = tid; i < HROWS * CGW; i += 256) {
      int r = i / CGW, c = i - r * CGW;
      int gy = ty0 - 7 + r, gx = tx0 - 8 + c * 4;
      float4 v;
      const bool yok = (gy >= 0) && (gy < H);
      if (yok && gx >= 0 && gx + 3 < W) {
        v = *(const float4*)(score2 + ibase + (size_t)gy * W + gx);
      } else if (yok) {
        const float* rp = score2 + ibase + (size_t)gy * W;
        v.x = (gx + 0 >= 0 && gx + 0 < W) ? rp[gx + 0] : -INFINITY;
        v.y = (gx + 1 >= 0 && gx + 1 < W) ? rp[gx + 1] : -INFINITY;
        v.z = (gx + 2 >= 0 && gx + 2 < W) ? rp[gx + 2] : -INFINITY;
        v.w = (gx + 3 >= 0 && gx + 3 < W) ? rp[gx + 3] : -INFINITY;
      } else {
        v = make_float4(-INFINITY, -INFINITY, -INFINITY, -INFINITY);
      }
      halo[r][c] = v;
    }
  }
  __syncthreads();

  // ---- phase 2: vertical 15-max. 160 threads: (col-group, 8-row run) ----
  if (tid < 160) {
    const int cg = tid % CGW;
    const int rr = tid / CGW;     // 0..7
    const int r0 = rr * 8;
    // core = max over relative rows 7..14 (shared by all 8 outputs)
    float4 core = halo[r0 + 7][cg];
    #pragma unroll
    for (int k = 8; k <= 14; k++) core = max4(core, halo[r0 + k][cg]);
    float4 a[7];
    #pragma unroll
    for (int k = 0; k < 7; k++) a[k] = halo[r0 + k][cg];
    float4 suf[7];                // suf[k] = max(v[15..15+k])
    suf[0] = halo[r0 + 15][cg];
    #pragma unroll
    for (int k = 1; k < 7; k++) suf[k] = max4(suf[k - 1], halo[r0 + 15 + k][cg]);
    // o[j] = max(v[j..j+14]) = core ∨ prefix(a[j..6]) ∨ suf[j-1]
    rmax[r0 + 7][cg] = max4(core, suf[6]);
    float4 pre = a[6];
    rmax[r0 + 6][cg] = max4(max4(core, pre), suf[5]);
    #pragma unroll
    for (int j = 5; j >= 1; j--) {
      pre = max4(a[j], pre);
      rmax[r0 + j][cg] = max4(max4(core, pre), suf[j - 1]);
    }
    pre = max4(a[0], pre);
    rmax[r0 + 0][cg] = max4(core, pre);
  }
  __syncthreads();

  // ---- phase 3: horizontal 15-max in registers + candidates + dense term ----
  const int row = tid >> 2;     // 0..63
  const int q   = tid & 3;      // 0..3 -> output cols q*16 .. q*16+15
  float r[32];                  // rmax halo-cols q*16 .. q*16+31
  #pragma unroll
  for (int g = 0; g < 8; g++) {
    float4 v = rmax[row][q * 4 + g];
    r[4 * g + 0] = v.x; r[4 * g + 1] = v.y; r[4 * g + 2] = v.z; r[4 * g + 3] = v.w;
  }
  // pooled[j] = max over r[j+1 .. j+15]  (output col x = q*16+j, window x±7)
  float pooled[16];
  #pragma unroll
  for (int m4 = 0; m4 < 4; m4++) {
    const int bse = 4 * m4;
    float core = r[bse + 4];
    #pragma unroll
    for (int t = 5; t <= 15; t++) core = fmaxf(core, r[bse + t]);
    pooled[bse + 0] = fmaxf(core, fmaxf(fmaxf(r[bse + 1], r[bse + 2]), r[bse + 3]));
    pooled[bse + 1] = fmaxf(core, fmaxf(fmaxf(r[bse + 2], r[bse + 3]), r[bse + 16]));
    pooled[bse + 2] = fmaxf(core, fmaxf(fmaxf(r[bse + 3], r[bse + 16]), r[bse + 17]));
    pooled[bse + 3] = fmaxf(core, fmaxf(fmaxf(r[bse + 16], r[bse + 17]), r[bse + 18]));
  }
  const int gy = ty0 + row;
  const int gx0 = tx0 + q * 16;
  const size_t rb = ibase + (size_t)gy * W + gx0;
  float t1 = 0.f; int mcnt = 0;
  #pragma unroll
  for (int k2 = 0; k2 < 4; k2++) {
    float4 sv = *(const float4*)(score1 + rb + 4 * k2);
    int4  mvv = *(const int4*)(mask + rb + 4 * k2);
    float4 cvv = halo[row + 7][q * 4 + 2 + k2];   // raw score2 centers, cols gx0+4*k2..+3
    float sc[4] = {sv.x, sv.y, sv.z, sv.w};
    int   mm[4] = {mvv.x, mvv.y, mvv.z, mvv.w};
    float cc[4] = {cvv.x, cvv.y, cvv.z, cvv.w};
    #pragma unroll
    for (int u = 0; u < 4; u++) {
      const int j = 4 * k2 + u;
      if (mm[u]) {
        t1 = fmaf(sc[u], sc[u], t1);
        mcnt++;
        const float s = cc[u];
        if (s == pooled[j] && s > 0.f) {
          int slot = atomicAdd(&ws->cand_count[b], 1);
          if (slot < CAP) {
            ws->cand_val[b * CAP + slot] = s;
            ws->cand_idx[b * CAP + slot] = gy * W + gx0 + j;
          }
        }
      }
    }
  }
  // block reduce
  #pragma unroll
  for (int off = 32; off > 0; off >>= 1) {
    t1 += __shfl_down(t1, off);
    mcnt += __shfl_down(mcnt, off);
  }
  if ((tid & 63) == 0) { wsumf[tid >> 6] = t1; wsumi[tid >> 6] = mcnt; }
  __syncthreads();
  if (tid == 0) {
    atomicAdd(&ws->term1[b], (double)((wsumf[0] + wsumf[1]) + (wsumf[2] + wsumf[3])));
    atomicAdd(&ws->masksum[b], (unsigned int)(wsumi[0] + wsumi[1] + wsumi[2] + wsumi[3]));
  }
}

// Fused exact top-k rank + Gaussian stamp correction. 16 slices of 256 candidates
// per image; candidate array replicated into LDS per block (broadcast reads).
__global__ __launch_bounds__(256) void k_rank_stamp(const float* __restrict__ score1,
                                                    const int* __restrict__ mask,
                                                    WS* __restrict__ ws) {
  const int b = blockIdx.x >> 4;
  const int slice = blockIdx.x & 15;
  int n = ws->cand_count[b]; if (n > CAP) n = CAP;
  const int i0 = slice * 256;
  if (i0 >= n) return;
  const int nPad = (n + 3) & ~3;
  __shared__ __align__(16) float sval[CAP];
  __shared__ __align__(16) int   sidx[CAP];
  __shared__ float cred[4];
  const int tid = threadIdx.x;
  for (int j = tid; j < nPad; j += 256) {
    sval[j] = (j < n) ? ws->cand_val[b * CAP + j] : -1.f;
    sidx[j] = (j < n) ? ws->cand_idx[b * CAP + j] : -1;
  }
  __syncthreads();
  const int i = i0 + tid;
  float contrib = 0.f;
  if (i < n) {
    const float vi = sval[i];
    const int   xi = sidx[i];
    int rank = 0;
    for (int j = 0; j < nPad; j += 4) {
      float4 v = *(const float4*)&sval[j];
      rank += (v.x > vi) + (v.y > vi) + (v.z > vi) + (v.w > vi);
      if (v.x == vi || v.y == vi || v.z == vi || v.w == vi) {   // rare (self + exact ties)
        if (v.x == vi && sidx[j + 0] < xi) rank++;
        if (v.y == vi && sidx[j + 1] < xi) rank++;
        if (v.z == vi && sidx[j + 2] < xi) rank++;
        if (v.w == vi && sidx[j + 3] < xi) rank++;
      }
    }
    if (rank < TOPK) {
      const int cy = xi >> 10, cx = xi & 1023;
      const size_t ib2 = (size_t)b * ((size_t)H * W);
      #pragma unroll
      for (int dy = -3; dy <= 3; dy++) {
        const int py = cy + dy;
        if (py < 0 || py >= H) continue;
        const float wy = GW[dy + 3];
        const float* s1r = score1 + ib2 + (size_t)py * W;
        const int*   mr  = mask   + ib2 + (size_t)py * W;
        #pragma unroll
        for (int dx = -3; dx <= 3; dx++) {
          const int px = cx + dx;
          if (px < 0 || px >= W) continue;
          if (mr[px]) {
            const float w = wy * GW[dx + 3];
            contrib += w * w - 2.f * s1r[px] * w;
          }
        }
      }
    }
  }
  #pragma unroll
  for (int off = 32; off > 0; off >>= 1) contrib += __shfl_down(contrib, off);
  if ((tid & 63) == 0) cred[tid >> 6] = contrib;
  __syncthreads();
  if (tid == 0)
    atomicAdd(&ws->corr[b], (double)((cred[0] + cred[1]) + (cred[2] + cred[3])));
}

__global__ void k_final(WS* __restrict__ ws, float* __restrict__ out) {
  if (threadIdx.x == 0 && blockIdx.x == 0) {
    double acc = 0.0;
    for (int b = 0; b < BATCH; b++) {
      double denom = (double)ws->masksum[b];
      if (denom < 1e-8) denom = 1e-8;
      acc += (ws->term1[b] + ws->corr[b]) / denom;
    }
    out[0] = (float)(acc / BATCH);
  }
}

extern "C" void kernel_launch(void* const* d_in, const int* in_sizes, int n_in,
                              void* d_out, int out_size, void* d_ws, size_t ws_size,
                              hipStream_t stream) {
  const float* score1 = (const float*)d_in[0];
  const float* score2 = (const float*)d_in[1];
  const int*   mask   = (const int*)d_in[2];
  float* out = (float*)d_out;
  WS* ws = (WS*)d_ws;

  k_zero<<<1, 64, 0, stream>>>(ws);
  k_nms<<<BATCH * 256, 256, 0, stream>>>(score1, score2, mask, ws);
  k_rank_stamp<<<BATCH * 16, 256, 0, stream>>>(score1, mask, ws);
  k_final<<<1, 1, 0, stream>>>(ws, out);
}

// Round 3
// 246.401 us; speedup vs baseline: 2.6183x; 2.1810x over previous
//
#include <hip/hip_runtime.h>
#include <math.h>

#define BATCH 16
#define H 1024
#define W 1024
#define TR 32            // tile rows
#define TC 64            // tile cols
#define HR 46            // halo rows = TR + 14
#define CGW 20           // float4 groups per halo row (80 floats: tx0-8 .. tx0+71)
#define CGP 21           // padded stride (336B) to spread banks
#define TILES_PER_IMG 512   // (1024/32)*(1024/64)
#define TOTTILES (BATCH * TILES_PER_IMG)
#define GRID_NMS 4096    // 2 tiles per block
#define CAP 4096
#define TOPK 2048
#define BCAP 64          // per-tile candidate cap (8-separation bound ~45)

struct WS {
  double term1[BATCH];
  double corr[BATCH];
  unsigned int masksum[BATCH];
  int cand_count[BATCH];
  float cand_val[BATCH * CAP];
  int   cand_idx[BATCH * CAP];
};

// ks=7 sigma=1 normalized Gaussian (validated absmax 0.0 in R1/R2)
__constant__ float GW[7] = {
  0.004433048175f, 0.054005582623f, 0.242036229376f, 0.399050279652f,
  0.242036229376f, 0.054005582623f, 0.004433048175f
};

__device__ __forceinline__ float4 max4(float4 a, float4 b) {
  float4 r;
  r.x = fmaxf(a.x, b.x); r.y = fmaxf(a.y, b.y);
  r.z = fmaxf(a.z, b.z); r.w = fmaxf(a.w, b.w);
  return r;
}

__global__ void k_zero(WS* ws) {
  int t = threadIdx.x;
  if (t < BATCH) {
    ws->term1[t] = 0.0;
    ws->corr[t] = 0.0;
    ws->masksum[t] = 0u;
    ws->cand_count[t] = 0;
  }
}

__global__ __launch_bounds__(256, 4) void k_nms(const float* __restrict__ score1,
                                                const float* __restrict__ score2,
                                                const int* __restrict__ mask,
                                                WS* __restrict__ ws) {
  __shared__ float4 halo[HR][CGP];   // halo[r][c] ~ (ty0-7+r, tx0-8+4c)
  __shared__ float4 rmax[TR][CGP];   // vertical 15-max for out rows
  __shared__ float s_cv[BCAP];
  __shared__ int   s_ci[BCAP];
  __shared__ int   s_cnt;
  __shared__ int   s_base;
  __shared__ float wsumf[4];
  __shared__ int   wsumi[4];
  const int tid = threadIdx.x;

  for (int t = blockIdx.x; t < TOTTILES; t += GRID_NMS) {
    const int b  = t >> 9;
    const int tt = t & 511;
    const int ty0 = (tt >> 4) << 5;    // 0,32,...,992
    const int tx0 = (tt & 15) << 6;    // 0,64,...,960
    const size_t ibase = (size_t)b * ((size_t)H * W);

    __syncthreads();                   // protect LDS reuse across tile loop
    if (tid == 0) s_cnt = 0;

    // ---- phase 1a: issue ALL global loads up front ----
    float4 st[4];
    int hr_[4], hc_[4];
    const bool interior = (ty0 >= 7) && (ty0 + 38 < H) && (tx0 >= 8) && (tx0 + 71 < W);
    if (interior) {
      #pragma unroll
      for (int k = 0; k < 4; k++) {
        int i = tid + (k << 8);
        if (i < HR * CGW) {
          int r = i / CGW, c = i - r * CGW;
          hr_[k] = r; hc_[k] = c;
          st[k] = *((const float4*)(score2 + ibase + (size_t)(ty0 - 7 + r) * W + (tx0 - 8)) + c);
        }
      }
    } else {
      #pragma unroll
      for (int k = 0; k < 4; k++) {
        int i = tid + (k << 8);
        if (i < HR * CGW) {
          int r = i / CGW, c = i - r * CGW;
          hr_[k] = r; hc_[k] = c;
          int gy = ty0 - 7 + r, gx = tx0 - 8 + (c << 2);
          float vv[4] = {-INFINITY, -INFINITY, -INFINITY, -INFINITY};
          if (gy >= 0 && gy < H) {
            const float* rp = score2 + ibase + (size_t)gy * W;
            #pragma unroll
            for (int u = 0; u < 4; u++) {
              int gxu = gx + u;
              if (gxu >= 0 && gxu < W) vv[u] = rp[gxu];
            }
          }
          st[k] = make_float4(vv[0], vv[1], vv[2], vv[3]);
        }
      }
    }
    // prefetch this thread's 8 output px of score1/mask (always in-image)
    const int prow = tid >> 3;          // 0..31
    const int c8   = tid & 7;           // 0..7 -> cols c8*8 .. c8*8+7
    const size_t pb = ibase + (size_t)(ty0 + prow) * W + tx0 + (c8 << 3);
    const float4 s1a = *(const float4*)(score1 + pb);
    const float4 s1b = *(const float4*)(score1 + pb + 4);
    const int4  mka = *(const int4*)(mask + pb);
    const int4  mkb = *(const int4*)(mask + pb + 4);

    // ---- phase 1b: halo -> LDS ----
    #pragma unroll
    for (int k = 0; k < 4; k++) {
      int i = tid + (k << 8);
      if (i < HR * CGW) halo[hr_[k]][hc_[k]] = st[k];
    }
    __syncthreads();

    // ---- phase 2: vertical 15-max, 4-row runs (160 active threads) ----
    if (tid < 160) {
      const int rr = tid / 20;
      const int cg = tid - rr * 20;
      const int R0 = rr << 2;
      float4 core = halo[R0 + 3][cg];
      #pragma unroll
      for (int k = 4; k <= 14; k++) core = max4(core, halo[R0 + k][cg]);
      const float4 h0 = halo[R0][cg], h1 = halo[R0 + 1][cg], h2 = halo[R0 + 2][cg];
      const float4 h15 = halo[R0 + 15][cg], h16 = halo[R0 + 16][cg], h17 = halo[R0 + 17][cg];
      const float4 p2 = h2, p1 = max4(h1, p2), p0 = max4(h0, p1);
      const float4 sf15 = h15, sf16 = max4(sf15, h16), sf17 = max4(sf16, h17);
      rmax[R0 + 0][cg] = max4(core, p0);
      rmax[R0 + 1][cg] = max4(max4(core, p1), sf15);
      rmax[R0 + 2][cg] = max4(max4(core, p2), sf16);
      rmax[R0 + 3][cg] = max4(core, sf17);
    }
    __syncthreads();

    // ---- phase 3: horizontal 15-max in registers, 8 outputs/thread ----
    float r[24];
    #pragma unroll
    for (int g = 0; g < 6; g++) {
      float4 v = rmax[prow][(c8 << 1) + g];
      r[4 * g + 0] = v.x; r[4 * g + 1] = v.y; r[4 * g + 2] = v.z; r[4 * g + 3] = v.w;
    }
    // window for out col j (0..7) = r[j+1 .. j+15]
    float core = r[8];
    #pragma unroll
    for (int k = 9; k <= 15; k++) core = fmaxf(core, r[k]);
    const float q7 = r[7];
    const float q6 = fmaxf(r[6], q7);
    const float q5 = fmaxf(r[5], q6);
    const float q4 = fmaxf(r[4], q5);
    const float q3 = fmaxf(r[3], q4);
    const float q2 = fmaxf(r[2], q3);
    const float q1 = fmaxf(r[1], q2);
    float sa[7];
    sa[0] = r[16];
    #pragma unroll
    for (int k = 1; k < 7; k++) sa[k] = fmaxf(sa[k - 1], r[16 + k]);
    float pooled[8];
    pooled[0] = fmaxf(core, q1);
    pooled[1] = fmaxf(fmaxf(core, q2), sa[0]);
    pooled[2] = fmaxf(fmaxf(core, q3), sa[1]);
    pooled[3] = fmaxf(fmaxf(core, q4), sa[2]);
    pooled[4] = fmaxf(fmaxf(core, q5), sa[3]);
    pooled[5] = fmaxf(fmaxf(core, q6), sa[4]);
    pooled[6] = fmaxf(fmaxf(core, q7), sa[5]);
    pooled[7] = fmaxf(core, sa[6]);

    const float4 cva = halo[prow + 7][(c8 << 1) + 2];
    const float4 cvb = halo[prow + 7][(c8 << 1) + 3];
    const float sc[8] = {s1a.x, s1a.y, s1a.z, s1a.w, s1b.x, s1b.y, s1b.z, s1b.w};
    const int   mm[8] = {mka.x, mka.y, mka.z, mka.w, mkb.x, mkb.y, mkb.z, mkb.w};
    const float cc[8] = {cva.x, cva.y, cva.z, cva.w, cvb.x, cvb.y, cvb.z, cvb.w};
    float t1 = 0.f; int mcnt = 0;
    #pragma unroll
    for (int j = 0; j < 8; j++) {
      if (mm[j]) {
        t1 = fmaf(sc[j], sc[j], t1);
        mcnt++;
        const float s = cc[j];
        if (s == pooled[j] && s > 0.f) {
          int slot = atomicAdd(&s_cnt, 1);
          if (slot < BCAP) {
            s_cv[slot] = s;
            s_ci[slot] = (ty0 + prow) * W + tx0 + (c8 << 3) + j;
          }
        }
      }
    }
    #pragma unroll
    for (int off = 32; off > 0; off >>= 1) {
      t1 += __shfl_down(t1, off);
      mcnt += __shfl_down(mcnt, off);
    }
    if ((tid & 63) == 0) { wsumf[tid >> 6] = t1; wsumi[tid >> 6] = mcnt; }
    __syncthreads();
    if (tid == 0) {
      atomicAdd(&ws->term1[b], (double)((wsumf[0] + wsumf[1]) + (wsumf[2] + wsumf[3])));
      atomicAdd(&ws->masksum[b], (unsigned int)(wsumi[0] + wsumi[1] + wsumi[2] + wsumi[3]));
      int cnt = s_cnt; if (cnt > BCAP) cnt = BCAP;
      s_base = atomicAdd(&ws->cand_count[b], cnt);
    }
    __syncthreads();
    {
      int cnt = s_cnt; if (cnt > BCAP) cnt = BCAP;
      const int base = s_base;
      for (int j = tid; j < cnt; j += 256) {
        int g = base + j;
        if (g < CAP) {
          ws->cand_val[b * CAP + g] = s_cv[j];
          ws->cand_idx[b * CAP + g] = s_ci[j];
        }
      }
    }
  }
}

// Fused exact-rank top-k + wave-cooperative Gaussian stamps.
__global__ __launch_bounds__(256) void k_rank_stamp(const float* __restrict__ score1,
                                                    const int* __restrict__ mask,
                                                    WS* __restrict__ ws) {
  const int b = blockIdx.x >> 4;
  const int slice = blockIdx.x & 15;
  int n = ws->cand_count[b]; if (n > CAP) n = CAP;
  const int i0 = slice * 256;
  if (i0 >= n) return;
  __shared__ __align__(16) float sval[CAP];
  __shared__ __align__(16) int   sidx[CAP];
  __shared__ int s_keys[256];
  __shared__ int s_nk;
  __shared__ float cred[4];
  const int tid = threadIdx.x;
  if (tid == 0) s_nk = 0;
  const int nPad = (n + 3) & ~3;
  for (int j = tid; j < nPad; j += 256) {
    sval[j] = (j < n) ? ws->cand_val[b * CAP + j] : -1.f;
    sidx[j] = (j < n) ? ws->cand_idx[b * CAP + j] : -1;
  }
  __syncthreads();
  const int i = i0 + tid;
  if (i < n) {
    const float vi = sval[i];
    const int   xi = sidx[i];
    int rank = 0;
    for (int j = 0; j < nPad; j += 4) {
      float4 v = *(const float4*)&sval[j];
      rank += (v.x > vi) + (v.y > vi) + (v.z > vi) + (v.w > vi);
      if (v.x == vi || v.y == vi || v.z == vi || v.w == vi) {
        if (v.x == vi && sidx[j + 0] < xi) rank++;
        if (v.y == vi && sidx[j + 1] < xi) rank++;
        if (v.z == vi && sidx[j + 2] < xi) rank++;
        if (v.w == vi && sidx[j + 3] < xi) rank++;
      }
    }
    if (rank < TOPK) { int p = atomicAdd(&s_nk, 1); s_keys[p] = xi; }
  }
  __syncthreads();
  const int nk = s_nk;
  const int wv = tid >> 6, lane = tid & 63;
  float contrib = 0.f;
  const size_t ib2 = (size_t)b * ((size_t)H * W);
  if (lane < 49) {
    const int dy = lane / 7 - 3, dx = lane % 7 - 3;
    const float w0 = GW[dy + 3] * GW[dx + 3];
    for (int k = wv; k < nk; k += 4) {
      const int ci = s_keys[k];
      const int cy = ci >> 10, cx = ci & 1023;
      const int py = cy + dy, px = cx + dx;
      if (py >= 0 && py < H && px >= 0 && px < W) {
        const size_t gi = ib2 + (size_t)py * W + px;
        const int m = mask[gi];
        const float s1v = score1[gi];
        if (m) contrib += w0 * w0 - 2.f * s1v * w0;
      }
    }
  }
  #pragma unroll
  for (int off = 32; off > 0; off >>= 1) contrib += __shfl_down(contrib, off);
  if (lane == 0) cred[wv] = contrib;
  __syncthreads();
  if (tid == 0)
    atomicAdd(&ws->corr[b], (double)((cred[0] + cred[1]) + (cred[2] + cred[3])));
}

__global__ void k_final(WS* __restrict__ ws, float* __restrict__ out) {
  if (threadIdx.x == 0 && blockIdx.x == 0) {
    double acc = 0.0;
    for (int b = 0; b < BATCH; b++) {
      double denom = (double)ws->masksum[b];
      if (denom < 1e-8) denom = 1e-8;
      acc += (ws->term1[b] + ws->corr[b]) / denom;
    }
    out[0] = (float)(acc / BATCH);
  }
}

extern "C" void kernel_launch(void* const* d_in, const int* in_sizes, int n_in,
                              void* d_out, int out_size, void* d_ws, size_t ws_size,
                              hipStream_t stream) {
  const float* score1 = (const float*)d_in[0];
  const float* score2 = (const float*)d_in[1];
  const int*   mask   = (const int*)d_in[2];
  float* out = (float*)d_out;
  WS* ws = (WS*)d_ws;

  k_zero<<<1, 64, 0, stream>>>(ws);
  k_nms<<<GRID_NMS, 256, 0, stream>>>(score1, score2, mask, ws);
  k_rank_stamp<<<BATCH * 16, 256, 0, stream>>>(score1, mask, ws);
  k_final<<<1, 1, 0, stream>>>(ws, out);
}

// Round 4
// 234.475 us; speedup vs baseline: 2.7515x; 1.0509x over previous
//
#include <hip/hip_runtime.h>
#include <math.h>

#define BATCH 16
#define H 1024
#define W 1024
#define TR 32            // tile rows
#define HR 46            // halo rows = TR + 14
#define CGW 20           // float4 groups per halo row (80 floats: tx0-8 .. tx0+71)
#define CGP 21           // padded stride (336B)
#define TILES_PER_IMG 512   // (1024/32)*(1024/64)
#define TOTTILES (BATCH * TILES_PER_IMG)   // 8192
#define CAP 4096
#define TOPK 2048
#define BCAP 64

struct WS {
  double term1[BATCH];
  double corr[BATCH];
  unsigned int masksum[BATCH];
  int cand_count[BATCH];
  int keycount[BATCH];
  float cand_val[BATCH * CAP];
  int   cand_idx[BATCH * CAP];
  int   keys[BATCH * TOPK];
};

// ks=7 sigma=1 normalized Gaussian (validated absmax 0.0 R1-R3)
__constant__ float GW[7] = {
  0.004433048175f, 0.054005582623f, 0.242036229376f, 0.399050279652f,
  0.242036229376f, 0.054005582623f, 0.004433048175f
};

__device__ __forceinline__ float4 max4(float4 a, float4 b) {
  float4 r;
  r.x = fmaxf(a.x, b.x); r.y = fmaxf(a.y, b.y);
  r.z = fmaxf(a.z, b.z); r.w = fmaxf(a.w, b.w);
  return r;
}

__global__ void k_zero(WS* ws) {
  int t = threadIdx.x;
  if (t < BATCH) {
    ws->term1[t] = 0.0;
    ws->corr[t] = 0.0;
    ws->masksum[t] = 0u;
    ws->cand_count[t] = 0;
    ws->keycount[t] = 0;
  }
}

// One block per 32x64 tile.
__global__ __launch_bounds__(256, 4) void k_nms(const float* __restrict__ score1,
                                                const float* __restrict__ score2,
                                                const int* __restrict__ mask,
                                                WS* __restrict__ ws) {
  __shared__ float4 halo[HR][CGP];
  __shared__ float4 rmax[TR][CGP];
  __shared__ float s_cv[BCAP];
  __shared__ int   s_ci[BCAP];
  __shared__ int   s_cnt;
  __shared__ int   s_base;
  __shared__ float wsumf[4];
  __shared__ int   wsumi[4];
  const int tid = threadIdx.x;

  const int t = blockIdx.x;
  const int b  = t >> 9;
  const int tt = t & 511;
  const int ty0 = (tt >> 4) << 5;
  const int tx0 = (tt & 15) << 6;
  const size_t ibase = (size_t)b * ((size_t)H * W);

  if (tid == 0) s_cnt = 0;

  // ---- phase 1a: issue ALL global loads up front ----
  float4 st[4];
  int hr_[4], hc_[4];
  const bool interior = (ty0 >= 7) && (ty0 + 38 < H) && (tx0 >= 8) && (tx0 + 71 < W);
  if (interior) {
    #pragma unroll
    for (int k = 0; k < 4; k++) {
      int i = tid + (k << 8);
      if (i < HR * CGW) {
        int r = i / CGW, c = i - r * CGW;
        hr_[k] = r; hc_[k] = c;
        st[k] = *((const float4*)(score2 + ibase + (size_t)(ty0 - 7 + r) * W + (tx0 - 8)) + c);
      }
    }
  } else {
    #pragma unroll
    for (int k = 0; k < 4; k++) {
      int i = tid + (k << 8);
      if (i < HR * CGW) {
        int r = i / CGW, c = i - r * CGW;
        hr_[k] = r; hc_[k] = c;
        int gy = ty0 - 7 + r, gx = tx0 - 8 + (c << 2);
        float vv[4] = {-INFINITY, -INFINITY, -INFINITY, -INFINITY};
        if (gy >= 0 && gy < H) {
          const float* rp = score2 + ibase + (size_t)gy * W;
          #pragma unroll
          for (int u = 0; u < 4; u++) {
            int gxu = gx + u;
            if (gxu >= 0 && gxu < W) vv[u] = rp[gxu];
          }
        }
        st[k] = make_float4(vv[0], vv[1], vv[2], vv[3]);
      }
    }
  }
  const int prow = tid >> 3;
  const int c8   = tid & 7;
  const size_t pb = ibase + (size_t)(ty0 + prow) * W + tx0 + (c8 << 3);
  const float4 s1a = *(const float4*)(score1 + pb);
  const float4 s1b = *(const float4*)(score1 + pb + 4);
  const int4  mka = *(const int4*)(mask + pb);
  const int4  mkb = *(const int4*)(mask + pb + 4);

  // ---- phase 1b: halo -> LDS ----
  #pragma unroll
  for (int k = 0; k < 4; k++) {
    int i = tid + (k << 8);
    if (i < HR * CGW) halo[hr_[k]][hc_[k]] = st[k];
  }
  __syncthreads();

  // ---- phase 2: vertical 15-max ----
  if (tid < 160) {
    const int rr = tid / 20;
    const int cg = tid - rr * 20;
    const int R0 = rr << 2;
    float4 core = halo[R0 + 3][cg];
    #pragma unroll
    for (int k = 4; k <= 14; k++) core = max4(core, halo[R0 + k][cg]);
    const float4 h0 = halo[R0][cg], h1 = halo[R0 + 1][cg], h2 = halo[R0 + 2][cg];
    const float4 h15 = halo[R0 + 15][cg], h16 = halo[R0 + 16][cg], h17 = halo[R0 + 17][cg];
    const float4 p2 = h2, p1 = max4(h1, p2), p0 = max4(h0, p1);
    const float4 sf15 = h15, sf16 = max4(sf15, h16), sf17 = max4(sf16, h17);
    rmax[R0 + 0][cg] = max4(core, p0);
    rmax[R0 + 1][cg] = max4(max4(core, p1), sf15);
    rmax[R0 + 2][cg] = max4(max4(core, p2), sf16);
    rmax[R0 + 3][cg] = max4(core, sf17);
  }
  __syncthreads();

  // ---- phase 3: horizontal 15-max in registers, 8 outputs/thread ----
  float r[24];
  #pragma unroll
  for (int g = 0; g < 6; g++) {
    float4 v = rmax[prow][(c8 << 1) + g];
    r[4 * g + 0] = v.x; r[4 * g + 1] = v.y; r[4 * g + 2] = v.z; r[4 * g + 3] = v.w;
  }
  float core = r[8];
  #pragma unroll
  for (int k = 9; k <= 15; k++) core = fmaxf(core, r[k]);
  const float q7 = r[7];
  const float q6 = fmaxf(r[6], q7);
  const float q5 = fmaxf(r[5], q6);
  const float q4 = fmaxf(r[4], q5);
  const float q3 = fmaxf(r[3], q4);
  const float q2 = fmaxf(r[2], q3);
  const float q1 = fmaxf(r[1], q2);
  float sa[7];
  sa[0] = r[16];
  #pragma unroll
  for (int k = 1; k < 7; k++) sa[k] = fmaxf(sa[k - 1], r[16 + k]);
  float pooled[8];
  pooled[0] = fmaxf(core, q1);
  pooled[1] = fmaxf(fmaxf(core, q2), sa[0]);
  pooled[2] = fmaxf(fmaxf(core, q3), sa[1]);
  pooled[3] = fmaxf(fmaxf(core, q4), sa[2]);
  pooled[4] = fmaxf(fmaxf(core, q5), sa[3]);
  pooled[5] = fmaxf(fmaxf(core, q6), sa[4]);
  pooled[6] = fmaxf(fmaxf(core, q7), sa[5]);
  pooled[7] = fmaxf(core, sa[6]);

  const float4 cva = halo[prow + 7][(c8 << 1) + 2];
  const float4 cvb = halo[prow + 7][(c8 << 1) + 3];
  const float sc[8] = {s1a.x, s1a.y, s1a.z, s1a.w, s1b.x, s1b.y, s1b.z, s1b.w};
  const int   mm[8] = {mka.x, mka.y, mka.z, mka.w, mkb.x, mkb.y, mkb.z, mkb.w};
  const float cc[8] = {cva.x, cva.y, cva.z, cva.w, cvb.x, cvb.y, cvb.z, cvb.w};
  float t1 = 0.f; int mcnt = 0;
  #pragma unroll
  for (int j = 0; j < 8; j++) {
    if (mm[j]) {
      t1 = fmaf(sc[j], sc[j], t1);
      mcnt++;
      const float s = cc[j];
      if (s == pooled[j] && s > 0.f) {
        int slot = atomicAdd(&s_cnt, 1);
        if (slot < BCAP) {
          s_cv[slot] = s;
          s_ci[slot] = (ty0 + prow) * W + tx0 + (c8 << 3) + j;
        }
      }
    }
  }
  #pragma unroll
  for (int off = 32; off > 0; off >>= 1) {
    t1 += __shfl_down(t1, off);
    mcnt += __shfl_down(mcnt, off);
  }
  if ((tid & 63) == 0) { wsumf[tid >> 6] = t1; wsumi[tid >> 6] = mcnt; }
  __syncthreads();
  if (tid == 0) {
    atomicAdd(&ws->term1[b], (double)((wsumf[0] + wsumf[1]) + (wsumf[2] + wsumf[3])));
    atomicAdd(&ws->masksum[b], (unsigned int)(wsumi[0] + wsumi[1] + wsumi[2] + wsumi[3]));
    int cnt = s_cnt; if (cnt > BCAP) cnt = BCAP;
    s_base = atomicAdd(&ws->cand_count[b], cnt);
  }
  __syncthreads();
  {
    int cnt = s_cnt; if (cnt > BCAP) cnt = BCAP;
    const int base = s_base;
    for (int j = tid; j < cnt; j += 256) {
      int g = base + j;
      if (g < CAP) {
        ws->cand_val[b * CAP + g] = s_cv[j];
        ws->cand_idx[b * CAP + g] = s_ci[j];
      }
    }
  }
}

// Exact-rank top-k: writes compact key list.
__global__ __launch_bounds__(256) void k_rank(WS* __restrict__ ws) {
  const int b = blockIdx.x >> 4;
  const int slice = blockIdx.x & 15;
  int n = ws->cand_count[b]; if (n > CAP) n = CAP;
  const int i0 = slice * 256;
  if (i0 >= n) return;
  __shared__ __align__(16) float sval[CAP];
  __shared__ __align__(16) int   sidx[CAP];
  const int tid = threadIdx.x;
  const int nPad = (n + 3) & ~3;
  for (int j = tid; j < nPad; j += 256) {
    sval[j] = (j < n) ? ws->cand_val[b * CAP + j] : -1.f;
    sidx[j] = (j < n) ? ws->cand_idx[b * CAP + j] : -1;
  }
  __syncthreads();
  const int i = i0 + tid;
  if (i >= n) return;
  const float vi = sval[i];
  const int   xi = sidx[i];
  int rank = 0;
  for (int j = 0; j < nPad; j += 4) {
    float4 v = *(const float4*)&sval[j];
    rank += (v.x > vi) + (v.y > vi) + (v.z > vi) + (v.w > vi);
    if (v.x == vi || v.y == vi || v.z == vi || v.w == vi) {
      if (v.x == vi && sidx[j + 0] < xi) rank++;
      if (v.y == vi && sidx[j + 1] < xi) rank++;
      if (v.z == vi && sidx[j + 2] < xi) rank++;
      if (v.w == vi && sidx[j + 3] < xi) rank++;
    }
  }
  if (rank < TOPK) {
    int p = atomicAdd(&ws->keycount[b], 1);
    if (p < TOPK) ws->keys[b * TOPK + p] = xi;
  }
}

// Gaussian stamp correction: 8 threads per key (thread = one stamp row).
// 64 blocks/image x 256 threads -> 32 keys/block, all waves resident at once.
__global__ __launch_bounds__(256) void k_stamp(const float* __restrict__ score1,
                                               const int* __restrict__ mask,
                                               WS* __restrict__ ws) {
  const int b = blockIdx.x >> 6;
  const int kb = blockIdx.x & 63;
  const int tid = threadIdx.x;
  int nk = ws->keycount[b]; if (nk > TOPK) nk = TOPK;
  const int k = kb * 32 + (tid >> 3);
  const int sub = tid & 7;
  float contrib = 0.f;
  if (k < nk && sub < 7) {
    const int ci = ws->keys[b * TOPK + k];
    const int cy = ci >> 10, cx = ci & 1023;
    const int py = cy + sub - 3;
    if (py >= 0 && py < H) {
      const float wy = GW[sub];
      const size_t rbase = (size_t)b * ((size_t)H * W) + (size_t)py * W;
      #pragma unroll
      for (int dx = -3; dx <= 3; dx++) {
        const int px = cx + dx;
        if (px >= 0 && px < W) {
          const int m = mask[rbase + px];
          const float s1v = score1[rbase + px];
          if (m) {
            const float w = wy * GW[dx + 3];
            contrib += w * w - 2.f * s1v * w;
          }
        }
      }
    }
  }
  #pragma unroll
  for (int off = 32; off > 0; off >>= 1) contrib += __shfl_down(contrib, off);
  __shared__ float cred[4];
  if ((tid & 63) == 0) cred[tid >> 6] = contrib;
  __syncthreads();
  if (tid == 0)
    atomicAdd(&ws->corr[b], (double)((cred[0] + cred[1]) + (cred[2] + cred[3])));
}

__global__ void k_final(WS* __restrict__ ws, float* __restrict__ out) {
  if (threadIdx.x == 0 && blockIdx.x == 0) {
    double acc = 0.0;
    for (int b = 0; b < BATCH; b++) {
      double denom = (double)ws->masksum[b];
      if (denom < 1e-8) denom = 1e-8;
      acc += (ws->term1[b] + ws->corr[b]) / denom;
    }
    out[0] = (float)(acc / BATCH);
  }
}

extern "C" void kernel_launch(void* const* d_in, const int* in_sizes, int n_in,
                              void* d_out, int out_size, void* d_ws, size_t ws_size,
                              hipStream_t stream) {
  const float* score1 = (const float*)d_in[0];
  const float* score2 = (const float*)d_in[1];
  const int*   mask   = (const int*)d_in[2];
  float* out = (float*)d_out;
  WS* ws = (WS*)d_ws;

  k_zero<<<1, 64, 0, stream>>>(ws);
  k_nms<<<TOTTILES, 256, 0, stream>>>(score1, score2, mask, ws);
  k_rank<<<BATCH * 16, 256, 0, stream>>>(ws);
  k_stamp<<<BATCH * 64, 256, 0, stream>>>(score1, mask, ws);
  k_final<<<1, 1, 0, stream>>>(ws, out);
}

// Round 5
// 150.980 us; speedup vs baseline: 4.2731x; 1.5530x over previous
//
#include <hip/hip_runtime.h>
#include <math.h>

#define BATCH 16
#define H 1024
#define W 1024
#define TR 32            // tile rows
#define HR 46            // halo rows = TR + 14
#define CGW 20           // float4 groups per halo row (80 floats: tx0-8 .. tx0+71)
#define CGP 21           // padded stride (336B)
#define TOTTILES 8192    // 16 img * 512 tiles
#define CAP 4096
#define TOPK 2048
#define BCAP 64

struct WS {
  double term1[BATCH];
  double corr[BATCH];
  unsigned int masksum[BATCH];
  int cand_count[BATCH];
  int pad_[BATCH];                 // keep cand_val 16B-aligned (offset 448)
  float cand_val[BATCH * CAP];     // zeroed every call (rank pad-safety)
  int   cand_idx[BATCH * CAP];
};

// ks=7 sigma=1 normalized Gaussian (validated absmax 0.0 R1-R4)
__constant__ float GW[7] = {
  0.004433048175f, 0.054005582623f, 0.242036229376f, 0.399050279652f,
  0.242036229376f, 0.054005582623f, 0.004433048175f
};

__device__ __forceinline__ float4 max4(float4 a, float4 b) {
  float4 r;
  r.x = fmaxf(a.x, b.x); r.y = fmaxf(a.y, b.y);
  r.z = fmaxf(a.z, b.z); r.w = fmaxf(a.w, b.w);
  return r;
}

// Parallel zero of cand_val + scalars. grid 64 x 256 -> 16384 float4 = 16*4096 floats.
__global__ void k_zero(WS* ws) {
  const int g = blockIdx.x * 256 + threadIdx.x;
  ((float4*)ws->cand_val)[g] = make_float4(0.f, 0.f, 0.f, 0.f);
  if (blockIdx.x == 0 && threadIdx.x < BATCH) {
    const int t = threadIdx.x;
    ws->term1[t] = 0.0;
    ws->corr[t] = 0.0;
    ws->masksum[t] = 0u;
    ws->cand_count[t] = 0;
  }
}

// One block per 32x64 tile. LDS = halo only (~16KB) -> 8+ blocks/CU.
__global__ __launch_bounds__(256, 6) void k_nms(const float* __restrict__ score1,
                                                const float* __restrict__ score2,
                                                const int* __restrict__ mask,
                                                WS* __restrict__ ws) {
  __shared__ float4 halo[HR][CGP];
  __shared__ float s_cv[BCAP];
  __shared__ int   s_ci[BCAP];
  __shared__ int   s_cnt;
  __shared__ int   s_base;
  __shared__ float wsumf[4];
  __shared__ int   wsumi[4];
  const int tid = threadIdx.x;

  const int t = blockIdx.x;
  const int b  = t >> 9;
  const int tt = t & 511;
  const int ty0 = (tt >> 4) << 5;
  const int tx0 = (tt & 15) << 6;
  const size_t ibase = (size_t)b * ((size_t)H * W);

  if (tid == 0) s_cnt = 0;

  // ---- phase 1: issue ALL global loads, consume s1/mask IMMEDIATELY ----
  float4 st[4];
  int hr_[4], hc_[4];
  const bool interior = (ty0 >= 7) && (ty0 + 38 < H) && (tx0 >= 8) && (tx0 + 71 < W);
  if (interior) {
    #pragma unroll
    for (int k = 0; k < 4; k++) {
      int i = tid + (k << 8);
      if (i < HR * CGW) {
        int r = i / CGW, c = i - r * CGW;
        hr_[k] = r; hc_[k] = c;
        st[k] = *((const float4*)(score2 + ibase + (size_t)(ty0 - 7 + r) * W + (tx0 - 8)) + c);
      }
    }
  } else {
    #pragma unroll
    for (int k = 0; k < 4; k++) {
      int i = tid + (k << 8);
      if (i < HR * CGW) {
        int r = i / CGW, c = i - r * CGW;
        hr_[k] = r; hc_[k] = c;
        int gy = ty0 - 7 + r, gx = tx0 - 8 + (c << 2);
        float vv[4] = {-INFINITY, -INFINITY, -INFINITY, -INFINITY};
        if (gy >= 0 && gy < H) {
          const float* rp = score2 + ibase + (size_t)gy * W;
          #pragma unroll
          for (int u = 0; u < 4; u++) {
            int gxu = gx + u;
            if (gxu >= 0 && gxu < W) vv[u] = rp[gxu];
          }
        }
        st[k] = make_float4(vv[0], vv[1], vv[2], vv[3]);
      }
    }
  }
  const int prow = tid >> 3;          // 0..31
  const int c8   = tid & 7;           // 0..7
  const size_t pb = ibase + (size_t)(ty0 + prow) * W + tx0 + (c8 << 3);
  const float4 s1a = *(const float4*)(score1 + pb);
  const float4 s1b = *(const float4*)(score1 + pb + 4);
  const int4  mka = *(const int4*)(mask + pb);
  const int4  mkb = *(const int4*)(mask + pb + 4);

  // consume now: dense term + mask bits (loads cannot sink past this)
  float t1 = 0.f; int mcnt = 0; unsigned int mbits = 0;
  {
    const float sc[8] = {s1a.x, s1a.y, s1a.z, s1a.w, s1b.x, s1b.y, s1b.z, s1b.w};
    const int   mm[8] = {mka.x, mka.y, mka.z, mka.w, mkb.x, mkb.y, mkb.z, mkb.w};
    #pragma unroll
    for (int j = 0; j < 8; j++) {
      if (mm[j]) { t1 = fmaf(sc[j], sc[j], t1); mcnt++; mbits |= (1u << j); }
    }
  }

  // halo -> LDS
  #pragma unroll
  for (int k = 0; k < 4; k++) {
    int i = tid + (k << 8);
    if (i < HR * CGW) halo[hr_[k]][hc_[k]] = st[k];
  }
  __syncthreads();

  // ---- phase 2: vertical 15-max into REGISTERS + capture center values ----
  float4 vr0, vr1, vr2, vr3;
  int R0 = 0, cg = 0;
  if (tid < 160) {
    const int rr = tid / 20;
    cg = tid - rr * 20;
    R0 = rr << 2;
    float4 core = halo[R0 + 3][cg];
    #pragma unroll
    for (int k = 4; k <= 14; k++) core = max4(core, halo[R0 + k][cg]);
    const float4 h0 = halo[R0][cg], h1 = halo[R0 + 1][cg], h2 = halo[R0 + 2][cg];
    const float4 h15 = halo[R0 + 15][cg], h16 = halo[R0 + 16][cg], h17 = halo[R0 + 17][cg];
    const float4 p2 = h2, p1 = max4(h1, p2), p0 = max4(h0, p1);
    const float4 sf15 = h15, sf16 = max4(sf15, h16), sf17 = max4(sf16, h17);
    vr0 = max4(core, p0);
    vr1 = max4(max4(core, p1), sf15);
    vr2 = max4(max4(core, p2), sf16);
    vr3 = max4(core, sf17);
  }
  const float4 cva = halo[prow + 7][(c8 << 1) + 2];   // raw score2 centers
  const float4 cvb = halo[prow + 7][(c8 << 1) + 3];
  __syncthreads();

  // ---- phase 3: write vertical maxes in-place into halo rows 0..31 ----
  if (tid < 160) {
    halo[R0 + 0][cg] = vr0;
    halo[R0 + 1][cg] = vr1;
    halo[R0 + 2][cg] = vr2;
    halo[R0 + 3][cg] = vr3;
  }
  __syncthreads();

  // ---- phase 4: horizontal 15-max in registers + emit ----
  float r[24];
  #pragma unroll
  for (int g = 0; g < 6; g++) {
    float4 v = halo[prow][(c8 << 1) + g];
    r[4 * g + 0] = v.x; r[4 * g + 1] = v.y; r[4 * g + 2] = v.z; r[4 * g + 3] = v.w;
  }
  float core = r[8];
  #pragma unroll
  for (int k = 9; k <= 15; k++) core = fmaxf(core, r[k]);
  const float q7 = r[7];
  const float q6 = fmaxf(r[6], q7);
  const float q5 = fmaxf(r[5], q6);
  const float q4 = fmaxf(r[4], q5);
  const float q3 = fmaxf(r[3], q4);
  const float q2 = fmaxf(r[2], q3);
  const float q1 = fmaxf(r[1], q2);
  float sa[7];
  sa[0] = r[16];
  #pragma unroll
  for (int k = 1; k < 7; k++) sa[k] = fmaxf(sa[k - 1], r[16 + k]);
  float pooled[8];
  pooled[0] = fmaxf(core, q1);
  pooled[1] = fmaxf(fmaxf(core, q2), sa[0]);
  pooled[2] = fmaxf(fmaxf(core, q3), sa[1]);
  pooled[3] = fmaxf(fmaxf(core, q4), sa[2]);
  pooled[4] = fmaxf(fmaxf(core, q5), sa[3]);
  pooled[5] = fmaxf(fmaxf(core, q6), sa[4]);
  pooled[6] = fmaxf(fmaxf(core, q7), sa[5]);
  pooled[7] = fmaxf(core, sa[6]);

  const float cc[8] = {cva.x, cva.y, cva.z, cva.w, cvb.x, cvb.y, cvb.z, cvb.w};
  #pragma unroll
  for (int j = 0; j < 8; j++) {
    if ((mbits >> j) & 1u) {
      const float s = cc[j];
      if (s == pooled[j] && s > 0.f) {
        int slot = atomicAdd(&s_cnt, 1);
        if (slot < BCAP) {
          s_cv[slot] = s;
          s_ci[slot] = (ty0 + prow) * W + tx0 + (c8 << 3) + j;
        }
      }
    }
  }
  #pragma unroll
  for (int off = 32; off > 0; off >>= 1) {
    t1 += __shfl_down(t1, off);
    mcnt += __shfl_down(mcnt, off);
  }
  if ((tid & 63) == 0) { wsumf[tid >> 6] = t1; wsumi[tid >> 6] = mcnt; }
  __syncthreads();
  if (tid == 0) {
    atomicAdd(&ws->term1[b], (double)((wsumf[0] + wsumf[1]) + (wsumf[2] + wsumf[3])));
    atomicAdd(&ws->masksum[b], (unsigned int)(wsumi[0] + wsumi[1] + wsumi[2] + wsumi[3]));
    int cnt = s_cnt; if (cnt > BCAP) cnt = BCAP;
    s_base = atomicAdd(&ws->cand_count[b], cnt);
  }
  __syncthreads();
  {
    int cnt = s_cnt; if (cnt > BCAP) cnt = BCAP;
    const int base = s_base;
    for (int j = tid; j < cnt; j += 256) {
      int g = base + j;
      if (g < CAP) {
        ws->cand_val[b * CAP + g] = s_cv[j];
        ws->cand_idx[b * CAP + g] = s_ci[j];
      }
    }
  }
}

// Fused exact-rank + stamp: 64 cands/block, 4 waves split the j-scan 4-way.
// grid = 16 img x 64 slices = 1024 blocks.
__global__ __launch_bounds__(256, 4) void k_rankstamp(const float* __restrict__ score1,
                                                      const int* __restrict__ mask,
                                                      WS* __restrict__ ws) {
  const int b = blockIdx.x >> 6;
  const int slice = blockIdx.x & 63;
  int n = ws->cand_count[b]; if (n > CAP) n = CAP;
  const int i0 = slice << 6;
  if (i0 >= n) return;
  __shared__ __align__(16) float sval[CAP];
  __shared__ __align__(16) int   sidx[CAP];
  __shared__ int   s_prank[4][64];
  __shared__ int   s_keys[BCAP];
  __shared__ int   s_nk;
  __shared__ float cred[4];
  const int tid = threadIdx.x;
  const int nf4 = (n + 3) >> 2;

  const float4* gv = (const float4*)(ws->cand_val + b * CAP);
  const int4*   gi = (const int4*)(ws->cand_idx + b * CAP);
  for (int j = tid; j < nf4; j += 256) {
    ((float4*)sval)[j] = gv[j];
    ((int4*)sidx)[j]   = gi[j];
  }
  __syncthreads();

  const int w = tid >> 6, l = tid & 63;
  const int ci = i0 + l;                 // < CAP always
  const float vi = sval[ci];
  const int   xi = sidx[ci];
  const int q = (nf4 + 3) >> 2;
  int lo = w * q; if (lo > nf4) lo = nf4;
  int hi = lo + q; if (hi > nf4) hi = nf4;
  int rank = 0;
  int j = lo;
  for (; j + 4 <= hi; j += 4) {
    #pragma unroll
    for (int u = 0; u < 4; u++) {
      const float4 v = ((const float4*)sval)[j + u];
      const int4  iv = ((const int4*)sidx)[j + u];
      rank += (v.x > vi) + (v.y > vi) + (v.z > vi) + (v.w > vi);
      rank += (v.x == vi && iv.x < xi);
      rank += (v.y == vi && iv.y < xi);
      rank += (v.z == vi && iv.z < xi);
      rank += (v.w == vi && iv.w < xi);
    }
  }
  for (; j < hi; j++) {
    const float4 v = ((const float4*)sval)[j];
    const int4  iv = ((const int4*)sidx)[j];
    rank += (v.x > vi) + (v.y > vi) + (v.z > vi) + (v.w > vi);
    rank += (v.x == vi && iv.x < xi);
    rank += (v.y == vi && iv.y < xi);
    rank += (v.z == vi && iv.z < xi);
    rank += (v.w == vi && iv.w < xi);
  }
  s_prank[w][l] = rank;
  __syncthreads();

  if (tid < 64) {
    const int rtot = s_prank[0][tid] + s_prank[1][tid] + s_prank[2][tid] + s_prank[3][tid];
    const bool sel = (i0 + tid < n) && (rtot < TOPK);
    const unsigned long long bal = __ballot(sel);
    if (sel) {
      const int pos = __popcll(bal & ((1ull << tid) - 1ull));
      s_keys[pos] = sidx[i0 + tid];
    }
    if (tid == 0) s_nk = (int)__popcll(bal);
  }
  __syncthreads();
  const int nk = s_nk;

  // stamps: 8 threads per key (thread = row), branchless clamped loads
  float contrib = 0.f;
  const int sub = tid & 7;
  const size_t ib2 = (size_t)b * ((size_t)H * W);
  #pragma unroll
  for (int rnd = 0; rnd < 2; rnd++) {
    const int k = (tid >> 3) + (rnd << 5);
    if (k < nk && sub < 7) {
      const int ck = s_keys[k];
      const int cy = ck >> 10, cx = ck & 1023;
      const int py = cy + sub - 3;
      const float wy = GW[sub] * ((py >= 0 && py < H) ? 1.f : 0.f);
      const int pyc = min(max(py, 0), H - 1);
      const float* s1r = score1 + ib2 + (size_t)pyc * W;
      const int*   mr  = mask   + ib2 + (size_t)pyc * W;
      #pragma unroll
      for (int dx = -3; dx <= 3; dx++) {
        const int px = cx + dx;
        const float wv = wy * GW[dx + 3] * ((px >= 0 && px < W) ? 1.f : 0.f);
        const int pxc = min(max(px, 0), W - 1);
        const float mf = (mr[pxc] != 0) ? 1.f : 0.f;
        contrib += mf * wv * (wv - 2.f * s1r[pxc]);
      }
    }
  }
  #pragma unroll
  for (int off = 32; off > 0; off >>= 1) contrib += __shfl_down(contrib, off);
  if ((tid & 63) == 0) cred[tid >> 6] = contrib;
  __syncthreads();
  if (tid == 0)
    atomicAdd(&ws->corr[b], (double)((cred[0] + cred[1]) + (cred[2] + cred[3])));
}

__global__ void k_final(WS* __restrict__ ws, float* __restrict__ out) {
  const int t = threadIdx.x;   // 64 threads, one wave
  double v = 0.0;
  if (t < BATCH) {
    double denom = (double)ws->masksum[t];
    if (denom < 1e-8) denom = 1e-8;
    v = (ws->term1[t] + ws->corr[t]) / denom;
  }
  #pragma unroll
  for (int off = 32; off > 0; off >>= 1) v += __shfl_down(v, off);
  if (t == 0) out[0] = (float)(v / BATCH);
}

extern "C" void kernel_launch(void* const* d_in, const int* in_sizes, int n_in,
                              void* d_out, int out_size, void* d_ws, size_t ws_size,
                              hipStream_t stream) {
  const float* score1 = (const float*)d_in[0];
  const float* score2 = (const float*)d_in[1];
  const int*   mask   = (const int*)d_in[2];
  float* out = (float*)d_out;
  WS* ws = (WS*)d_ws;

  k_zero<<<64, 256, 0, stream>>>(ws);
  k_nms<<<TOTTILES, 256, 0, stream>>>(score1, score2, mask, ws);
  k_rankstamp<<<BATCH * 64, 256, 0, stream>>>(score1, mask, ws);
  k_final<<<1, 64, 0, stream>>>(ws, out);
}

// Round 6
// 101.017 us; speedup vs baseline: 6.3866x; 1.4946x over previous
//
#include <hip/hip_runtime.h>
#include <math.h>

#define BATCH 16
#define H 1024
#define W 1024
#define HR 46            // halo rows = 32 + 14
#define CGW 20           // float4 groups per halo row (80 floats: tx0-8 .. tx0+71)
#define CGP 21           // padded stride (336B)
#define NTILES 8192      // 16 img * 512 tiles (32x64 each)
#define CAP 4096
#define TOPK 2048
#define BCAP 40          // per-tile candidate cap (8-separation bound: 32)

struct WS {
  double term1[BATCH];
  double corr[BATCH];
  unsigned int masksum[BATCH];
  int cand_count[BATCH];
  int   tile_cnt[NTILES];          // zeroed each call
  float pt1[NTILES * 4];           // per-wave dense partials (always written)
  int   pmc[NTILES * 4];
  float tile_val[NTILES * BCAP];
  int   tile_idx[NTILES * BCAP];
  float ccand_val[BATCH * CAP];    // zeroed each call (rank pad-safety)
  int   ccand_idx[BATCH * CAP];
};

// ks=7 sigma=1 normalized Gaussian (validated absmax 0.0 R1-R5)
__constant__ float GW[7] = {
  0.004433048175f, 0.054005582623f, 0.242036229376f, 0.399050279652f,
  0.242036229376f, 0.054005582623f, 0.004433048175f
};

__device__ __forceinline__ float4 max4(float4 a, float4 b) {
  float4 r;
  r.x = fmaxf(a.x, b.x); r.y = fmaxf(a.y, b.y);
  r.z = fmaxf(a.z, b.z); r.w = fmaxf(a.w, b.w);
  return r;
}

// 64 blocks x 256: zero ccand_val (16384 f4), tile_cnt (2048 i4), scalars.
__global__ void k_zero(WS* ws) {
  const int g = blockIdx.x * 256 + threadIdx.x;
  ((float4*)ws->ccand_val)[g] = make_float4(0.f, 0.f, 0.f, 0.f);
  if (g < 2048) ((int4*)ws->tile_cnt)[g] = make_int4(0, 0, 0, 0);
  if (blockIdx.x == 0 && threadIdx.x < BATCH) {
    const int t = threadIdx.x;
    ws->term1[t] = 0.0;
    ws->corr[t] = 0.0;
    ws->masksum[t] = 0u;
    ws->cand_count[t] = 0;
  }
}

// One block per 32x64 tile. 2 barriers, NO hot atomics, no tail phase.
__global__ __launch_bounds__(256, 6) void k_nms(const float* __restrict__ score1,
                                                const float* __restrict__ score2,
                                                const int* __restrict__ mask,
                                                WS* __restrict__ ws) {
  __shared__ float4 halo[HR][CGP];
  __shared__ float4 rmax[32][CGP];
  const int tid = threadIdx.x;

  const int t = blockIdx.x;
  const int b  = t >> 9;
  const int tt = t & 511;
  const int ty0 = (tt >> 4) << 5;
  const int tx0 = (tt & 15) << 6;
  const size_t ibase = (size_t)b * ((size_t)H * W);

  // ---- phase 1: issue all global loads ----
  float4 st[4];
  int hr_[4], hc_[4];
  const bool interior = (ty0 >= 7) && (ty0 + 38 < H) && (tx0 >= 8) && (tx0 + 71 < W);
  if (interior) {
    #pragma unroll
    for (int k = 0; k < 4; k++) {
      int i = tid + (k << 8);
      if (i < HR * CGW) {
        int r = i / CGW, c = i - r * CGW;
        hr_[k] = r; hc_[k] = c;
        st[k] = *((const float4*)(score2 + ibase + (size_t)(ty0 - 7 + r) * W + (tx0 - 8)) + c);
      }
    }
  } else {
    #pragma unroll
    for (int k = 0; k < 4; k++) {
      int i = tid + (k << 8);
      if (i < HR * CGW) {
        int r = i / CGW, c = i - r * CGW;
        hr_[k] = r; hc_[k] = c;
        int gy = ty0 - 7 + r, gx = tx0 - 8 + (c << 2);
        float vv[4] = {-INFINITY, -INFINITY, -INFINITY, -INFINITY};
        if (gy >= 0 && gy < H) {
          const float* rp = score2 + ibase + (size_t)gy * W;
          #pragma unroll
          for (int u = 0; u < 4; u++) {
            int gxu = gx + u;
            if (gxu >= 0 && gxu < W) vv[u] = rp[gxu];
          }
        }
        st[k] = make_float4(vv[0], vv[1], vv[2], vv[3]);
      }
    }
  }
  const int prow = tid >> 3;          // 0..31
  const int c8   = tid & 7;           // 0..7
  const size_t pb = ibase + (size_t)(ty0 + prow) * W + tx0 + (c8 << 3);
  const float4 s1a = *(const float4*)(score1 + pb);
  const float4 s1b = *(const float4*)(score1 + pb + 4);
  const int4  mka = *(const int4*)(mask + pb);
  const int4  mkb = *(const int4*)(mask + pb + 4);

  #pragma unroll
  for (int k = 0; k < 4; k++) {
    int i = tid + (k << 8);
    if (i < HR * CGW) halo[hr_[k]][hc_[k]] = st[k];
  }
  __syncthreads();

  // ---- phase 2: vertical 15-max -> rmax LDS (160 active threads) ----
  if (tid < 160) {
    const int rr = tid / 20;
    const int cg = tid - rr * 20;
    const int R0 = rr << 2;
    float4 core = halo[R0 + 3][cg];
    #pragma unroll
    for (int k = 4; k <= 14; k++) core = max4(core, halo[R0 + k][cg]);
    const float4 h0 = halo[R0][cg], h1 = halo[R0 + 1][cg], h2 = halo[R0 + 2][cg];
    const float4 h15 = halo[R0 + 15][cg], h16 = halo[R0 + 16][cg], h17 = halo[R0 + 17][cg];
    const float4 p2 = h2, p1 = max4(h1, p2), p0 = max4(h0, p1);
    const float4 sf15 = h15, sf16 = max4(sf15, h16), sf17 = max4(sf16, h17);
    rmax[R0 + 0][cg] = max4(core, p0);
    rmax[R0 + 1][cg] = max4(max4(core, p1), sf15);
    rmax[R0 + 2][cg] = max4(max4(core, p2), sf16);
    rmax[R0 + 3][cg] = max4(core, sf17);
  }

  // dense term from registers (overlaps with phase 2 latency)
  float t1 = 0.f; int mcnt = 0; unsigned int mbits = 0;
  {
    const float sc[8] = {s1a.x, s1a.y, s1a.z, s1a.w, s1b.x, s1b.y, s1b.z, s1b.w};
    const int   mm[8] = {mka.x, mka.y, mka.z, mka.w, mkb.x, mkb.y, mkb.z, mkb.w};
    #pragma unroll
    for (int j = 0; j < 8; j++) {
      if (mm[j]) { t1 = fmaf(sc[j], sc[j], t1); mcnt++; mbits |= (1u << j); }
    }
  }
  __syncthreads();

  // ---- phase 3: horizontal 15-max in registers + emit ----
  float r[24];
  #pragma unroll
  for (int g = 0; g < 6; g++) {
    float4 v = rmax[prow][(c8 << 1) + g];
    r[4 * g + 0] = v.x; r[4 * g + 1] = v.y; r[4 * g + 2] = v.z; r[4 * g + 3] = v.w;
  }
  float core = r[8];
  #pragma unroll
  for (int k = 9; k <= 15; k++) core = fmaxf(core, r[k]);
  const float q7 = r[7];
  const float q6 = fmaxf(r[6], q7);
  const float q5 = fmaxf(r[5], q6);
  const float q4 = fmaxf(r[4], q5);
  const float q3 = fmaxf(r[3], q4);
  const float q2 = fmaxf(r[2], q3);
  const float q1 = fmaxf(r[1], q2);
  float sa[7];
  sa[0] = r[16];
  #pragma unroll
  for (int k = 1; k < 7; k++) sa[k] = fmaxf(sa[k - 1], r[16 + k]);
  float pooled[8];
  pooled[0] = fmaxf(core, q1);
  pooled[1] = fmaxf(fmaxf(core, q2), sa[0]);
  pooled[2] = fmaxf(fmaxf(core, q3), sa[1]);
  pooled[3] = fmaxf(fmaxf(core, q4), sa[2]);
  pooled[4] = fmaxf(fmaxf(core, q5), sa[3]);
  pooled[5] = fmaxf(fmaxf(core, q6), sa[4]);
  pooled[6] = fmaxf(fmaxf(core, q7), sa[5]);
  pooled[7] = fmaxf(core, sa[6]);

  const float4 cva = halo[prow + 7][(c8 << 1) + 2];   // raw score2 centers
  const float4 cvb = halo[prow + 7][(c8 << 1) + 3];
  const float cc[8] = {cva.x, cva.y, cva.z, cva.w, cvb.x, cvb.y, cvb.z, cvb.w};
  #pragma unroll
  for (int j = 0; j < 8; j++) {
    if ((mbits >> j) & 1u) {
      const float s = cc[j];
      if (s == pooled[j] && s > 0.f) {
        int slot = atomicAdd(&ws->tile_cnt[t], 1);   // per-tile address: cold
        if (slot < BCAP) {
          ws->tile_val[t * BCAP + slot] = s;
          ws->tile_idx[t * BCAP + slot] = (ty0 + prow) * W + tx0 + (c8 << 3) + j;
        }
      }
    }
  }
  // per-wave partials: plain stores, no atomics, no barrier
  #pragma unroll
  for (int off = 32; off > 0; off >>= 1) {
    t1 += __shfl_down(t1, off);
    mcnt += __shfl_down(mcnt, off);
  }
  if ((tid & 63) == 0) {
    ws->pt1[t * 4 + (tid >> 6)] = t1;
    ws->pmc[t * 4 + (tid >> 6)] = mcnt;
  }
}

// One block per image: sum partials, scan tile counts, compact candidates.
__global__ __launch_bounds__(256) void k_compact(WS* __restrict__ ws) {
  const int b = blockIdx.x;
  const int tid = threadIdx.x;
  const int lane = tid & 63, w = tid >> 6;
  __shared__ double sF[4];
  __shared__ int    sI[4];
  __shared__ int    wt[4];

  // 1) dense partials: 2048 each
  double tsum = 0.0; int msum = 0;
  for (int j = tid; j < 2048; j += 256) {
    tsum += (double)ws->pt1[b * 2048 + j];
    msum += ws->pmc[b * 2048 + j];
  }
  #pragma unroll
  for (int off = 32; off > 0; off >>= 1) {
    tsum += __shfl_down(tsum, off);
    msum += __shfl_down(msum, off);
  }
  if (lane == 0) { sF[w] = tsum; sI[w] = msum; }

  // 2) counts + scan (512 tiles, 2 per thread)
  const int tg = b * 512 + 2 * tid;
  int c0 = ws->tile_cnt[tg];     if (c0 > BCAP) c0 = BCAP;
  int c1 = ws->tile_cnt[tg + 1]; if (c1 > BCAP) c1 = BCAP;
  const int pairs = c0 + c1;
  int v = pairs;
  #pragma unroll
  for (int off = 1; off < 64; off <<= 1) {
    int u = __shfl_up(v, off);
    if (lane >= off) v += u;
  }
  if (lane == 63) wt[w] = v;
  __syncthreads();
  if (tid == 0) {
    ws->term1[b] = (sF[0] + sF[1]) + (sF[2] + sF[3]);
    ws->masksum[b] = (unsigned int)(sI[0] + sI[1] + sI[2] + sI[3]);
  }
  int wo = 0;
  #pragma unroll
  for (int k = 0; k < 4; k++) if (k < w) wo += wt[k];
  const int excl = v - pairs + wo;     // exclusive prefix for this thread's pair
  if (tid == 255) {
    int tot = excl + pairs;
    ws->cand_count[b] = (tot > CAP) ? CAP : tot;
  }
  // 3) copy
  float* dv = ws->ccand_val + b * CAP;
  int*   di = ws->ccand_idx + b * CAP;
  const float* sv0 = ws->tile_val + (size_t)tg * BCAP;
  const int*   si0 = ws->tile_idx + (size_t)tg * BCAP;
  for (int j = 0; j < c0; j++) {
    int o = excl + j;
    if (o < CAP) { dv[o] = sv0[j]; di[o] = si0[j]; }
  }
  for (int j = 0; j < c1; j++) {
    int o = excl + c0 + j;
    if (o < CAP) { dv[o] = sv0[BCAP + j]; di[o] = si0[BCAP + j]; }
  }
}

// Fused exact-rank + stamp: 64 cands/block, 4 waves split the j-scan 4-way.
__global__ __launch_bounds__(256, 4) void k_rankstamp(const float* __restrict__ score1,
                                                      const int* __restrict__ mask,
                                                      WS* __restrict__ ws) {
  const int b = blockIdx.x >> 6;
  const int slice = blockIdx.x & 63;
  int n = ws->cand_count[b]; if (n > CAP) n = CAP;
  const int i0 = slice << 6;
  if (i0 >= n) return;
  __shared__ __align__(16) float sval[CAP];
  __shared__ __align__(16) int   sidx[CAP];
  __shared__ int   s_prank[4][64];
  __shared__ int   s_keys[64];
  __shared__ int   s_nk;
  __shared__ float cred[4];
  const int tid = threadIdx.x;
  const int nf4 = (n + 3) >> 2;

  const float4* gv = (const float4*)(ws->ccand_val + b * CAP);
  const int4*   gi = (const int4*)(ws->ccand_idx + b * CAP);
  for (int j = tid; j < nf4; j += 256) {
    ((float4*)sval)[j] = gv[j];
    ((int4*)sidx)[j]   = gi[j];
  }
  __syncthreads();

  const int w = tid >> 6, l = tid & 63;
  const float vi = sval[i0 + l];
  const int   xi = sidx[i0 + l];
  const int q = (nf4 + 3) >> 2;
  int lo = w * q; if (lo > nf4) lo = nf4;
  int hi = lo + q; if (hi > nf4) hi = nf4;
  int rank = 0;
  int j = lo;
  for (; j + 4 <= hi; j += 4) {
    #pragma unroll
    for (int u = 0; u < 4; u++) {
      const float4 v = ((const float4*)sval)[j + u];
      const int4  iv = ((const int4*)sidx)[j + u];
      rank += (v.x > vi) + (v.y > vi) + (v.z > vi) + (v.w > vi);
      rank += (v.x == vi && iv.x < xi);
      rank += (v.y == vi && iv.y < xi);
      rank += (v.z == vi && iv.z < xi);
      rank += (v.w == vi && iv.w < xi);
    }
  }
  for (; j < hi; j++) {
    const float4 v = ((const float4*)sval)[j];
    const int4  iv = ((const int4*)sidx)[j];
    rank += (v.x > vi) + (v.y > vi) + (v.z > vi) + (v.w > vi);
    rank += (v.x == vi && iv.x < xi);
    rank += (v.y == vi && iv.y < xi);
    rank += (v.z == vi && iv.z < xi);
    rank += (v.w == vi && iv.w < xi);
  }
  s_prank[w][l] = rank;
  __syncthreads();

  if (tid < 64) {
    const int rtot = s_prank[0][tid] + s_prank[1][tid] + s_prank[2][tid] + s_prank[3][tid];
    const bool sel = (i0 + tid < n) && (rtot < TOPK);
    const unsigned long long bal = __ballot(sel);
    if (sel) {
      const int pos = __popcll(bal & ((1ull << tid) - 1ull));
      s_keys[pos] = sidx[i0 + tid];
    }
    if (tid == 0) s_nk = (int)__popcll(bal);
  }
  __syncthreads();
  const int nk = s_nk;

  float contrib = 0.f;
  const int sub = tid & 7;
  const size_t ib2 = (size_t)b * ((size_t)H * W);
  #pragma unroll
  for (int rnd = 0; rnd < 2; rnd++) {
    const int k = (tid >> 3) + (rnd << 5);
    if (k < nk && sub < 7) {
      const int ck = s_keys[k];
      const int cy = ck >> 10, cx = ck & 1023;
      const int py = cy + sub - 3;
      const float wy = GW[sub] * ((py >= 0 && py < H) ? 1.f : 0.f);
      const int pyc = min(max(py, 0), H - 1);
      const float* s1r = score1 + ib2 + (size_t)pyc * W;
      const int*   mr  = mask   + ib2 + (size_t)pyc * W;
      #pragma unroll
      for (int dx = -3; dx <= 3; dx++) {
        const int px = cx + dx;
        const float wv = wy * GW[dx + 3] * ((px >= 0 && px < W) ? 1.f : 0.f);
        const int pxc = min(max(px, 0), W - 1);
        const float mf = (mr[pxc] != 0) ? 1.f : 0.f;
        contrib += mf * wv * (wv - 2.f * s1r[pxc]);
      }
    }
  }
  #pragma unroll
  for (int off = 32; off > 0; off >>= 1) contrib += __shfl_down(contrib, off);
  if ((tid & 63) == 0) cred[tid >> 6] = contrib;
  __syncthreads();
  if (tid == 0)
    atomicAdd(&ws->corr[b], (double)((cred[0] + cred[1]) + (cred[2] + cred[3])));
}

__global__ void k_final(WS* __restrict__ ws, float* __restrict__ out) {
  const int t = threadIdx.x;
  double v = 0.0;
  if (t < BATCH) {
    double denom = (double)ws->masksum[t];
    if (denom < 1e-8) denom = 1e-8;
    v = (ws->term1[t] + ws->corr[t]) / denom;
  }
  #pragma unroll
  for (int off = 32; off > 0; off >>= 1) v += __shfl_down(v, off);
  if (t == 0) out[0] = (float)(v / BATCH);
}

extern "C" void kernel_launch(void* const* d_in, const int* in_sizes, int n_in,
                              void* d_out, int out_size, void* d_ws, size_t ws_size,
                              hipStream_t stream) {
  const float* score1 = (const float*)d_in[0];
  const float* score2 = (const float*)d_in[1];
  const int*   mask   = (const int*)d_in[2];
  float* out = (float*)d_out;
  WS* ws = (WS*)d_ws;

  k_zero<<<64, 256, 0, stream>>>(ws);
  k_nms<<<NTILES, 256, 0, stream>>>(score1, score2, mask, ws);
  k_compact<<<BATCH, 256, 0, stream>>>(ws);
  k_rankstamp<<<BATCH * 64, 256, 0, stream>>>(score1, mask, ws);
  k_final<<<1, 64, 0, stream>>>(ws, out);
}

// Round 7
// 82.181 us; speedup vs baseline: 7.8504x; 1.2292x over previous
//
#include <hip/hip_runtime.h>
#include <math.h>

#define BATCH 16
#define H 1024
#define W 1024
#define HR 46            // halo rows = 32 + 14
#define CGW 20           // float4 groups per halo row (80 floats: tx0-8 .. tx0+71)
#define CGP 21           // padded stride (336B)
#define NTILES 8192      // 16 img * 512 tiles (32x64 each)
#define CAP 4096
#define TOPK 2048
#define BCAP 40          // per-tile candidate cap (8-separation bound: 32)

struct WS {
  double term1[BATCH];
  double corr[BATCH];
  unsigned int masksum[BATCH];
  int cand_count[BATCH];
  int   tile_cnt[NTILES];          // stored (not accumulated) by k_nms every call
  float pt1[NTILES * 4];           // per-wave dense partials (always written)
  int   pmc[NTILES * 4];
  float tile_val[NTILES * BCAP];
  int   tile_idx[NTILES * BCAP];
  float ccand_val[BATCH * CAP];    // [0..cand_count) + 3-elem zero pad written by k_compact
  int   ccand_idx[BATCH * CAP];
};

// ks=7 sigma=1 normalized Gaussian (validated absmax 0.0 R1-R6)
__constant__ float GW[7] = {
  0.004433048175f, 0.054005582623f, 0.242036229376f, 0.399050279652f,
  0.242036229376f, 0.054005582623f, 0.004433048175f
};

__device__ __forceinline__ float4 max4(float4 a, float4 b) {
  float4 r;
  r.x = fmaxf(a.x, b.x); r.y = fmaxf(a.y, b.y);
  r.z = fmaxf(a.z, b.z); r.w = fmaxf(a.w, b.w);
  return r;
}

// One block per 32x64 tile. XCD-chunked swizzle; 3 barriers; zero global atomics.
__global__ __launch_bounds__(256, 6) void k_nms(const float* __restrict__ score1,
                                                const float* __restrict__ score2,
                                                const int* __restrict__ mask,
                                                WS* __restrict__ ws) {
  __shared__ float4 halo[HR][CGP];
  __shared__ float4 rmax[32][CGP];
  __shared__ float s_cv[BCAP];
  __shared__ int   s_ci[BCAP];
  __shared__ int   s_cnt;
  const int tid = threadIdx.x;

  // bijective XCD swizzle: hw blocks i, i+8 (same XCD) -> adjacent tiles
  const int t = (blockIdx.x & 7) * (NTILES / 8) + (blockIdx.x >> 3);
  const int b  = t >> 9;
  const int tt = t & 511;
  const int ty0 = (tt >> 4) << 5;
  const int tx0 = (tt & 15) << 6;
  const size_t ibase = (size_t)b * ((size_t)H * W);

  if (tid == 0) s_cnt = 0;

  // ---- phase 1: issue all global loads ----
  float4 st[4];
  int hr_[4], hc_[4];
  const bool interior = (ty0 >= 7) && (ty0 + 38 < H) && (tx0 >= 8) && (tx0 + 71 < W);
  if (interior) {
    #pragma unroll
    for (int k = 0; k < 4; k++) {
      int i = tid + (k << 8);
      if (i < HR * CGW) {
        int r = i / CGW, c = i - r * CGW;
        hr_[k] = r; hc_[k] = c;
        st[k] = *((const float4*)(score2 + ibase + (size_t)(ty0 - 7 + r) * W + (tx0 - 8)) + c);
      }
    }
  } else {
    #pragma unroll
    for (int k = 0; k < 4; k++) {
      int i = tid + (k << 8);
      if (i < HR * CGW) {
        int r = i / CGW, c = i - r * CGW;
        hr_[k] = r; hc_[k] = c;
        int gy = ty0 - 7 + r, gx = tx0 - 8 + (c << 2);
        float vv[4] = {-INFINITY, -INFINITY, -INFINITY, -INFINITY};
        if (gy >= 0 && gy < H) {
          const float* rp = score2 + ibase + (size_t)gy * W;
          #pragma unroll
          for (int u = 0; u < 4; u++) {
            int gxu = gx + u;
            if (gxu >= 0 && gxu < W) vv[u] = rp[gxu];
          }
        }
        st[k] = make_float4(vv[0], vv[1], vv[2], vv[3]);
      }
    }
  }
  const int prow = tid >> 3;          // 0..31
  const int c8   = tid & 7;           // 0..7
  const size_t pb = ibase + (size_t)(ty0 + prow) * W + tx0 + (c8 << 3);
  const float4 s1a = *(const float4*)(score1 + pb);
  const float4 s1b = *(const float4*)(score1 + pb + 4);
  const int4  mka = *(const int4*)(mask + pb);
  const int4  mkb = *(const int4*)(mask + pb + 4);

  #pragma unroll
  for (int k = 0; k < 4; k++) {
    int i = tid + (k << 8);
    if (i < HR * CGW) halo[hr_[k]][hc_[k]] = st[k];
  }
  __syncthreads();

  // ---- phase 2: vertical 15-max -> rmax (160 active threads) ----
  if (tid < 160) {
    const int rr = tid / 20;
    const int cg = tid - rr * 20;
    const int R0 = rr << 2;
    float4 core = halo[R0 + 3][cg];
    #pragma unroll
    for (int k = 4; k <= 14; k++) core = max4(core, halo[R0 + k][cg]);
    const float4 h0 = halo[R0][cg], h1 = halo[R0 + 1][cg], h2 = halo[R0 + 2][cg];
    const float4 h15 = halo[R0 + 15][cg], h16 = halo[R0 + 16][cg], h17 = halo[R0 + 17][cg];
    const float4 p2 = h2, p1 = max4(h1, p2), p0 = max4(h0, p1);
    const float4 sf15 = h15, sf16 = max4(sf15, h16), sf17 = max4(sf16, h17);
    rmax[R0 + 0][cg] = max4(core, p0);
    rmax[R0 + 1][cg] = max4(max4(core, p1), sf15);
    rmax[R0 + 2][cg] = max4(max4(core, p2), sf16);
    rmax[R0 + 3][cg] = max4(core, sf17);
  }

  // dense term from registers (overlaps phase-2 latency)
  float t1 = 0.f; int mcnt = 0; unsigned int mbits = 0;
  {
    const float sc[8] = {s1a.x, s1a.y, s1a.z, s1a.w, s1b.x, s1b.y, s1b.z, s1b.w};
    const int   mm[8] = {mka.x, mka.y, mka.z, mka.w, mkb.x, mkb.y, mkb.z, mkb.w};
    #pragma unroll
    for (int j = 0; j < 8; j++) {
      if (mm[j]) { t1 = fmaf(sc[j], sc[j], t1); mcnt++; mbits |= (1u << j); }
    }
  }
  __syncthreads();

  // ---- phase 3: horizontal 15-max in registers + emit to LDS ----
  float r[24];
  #pragma unroll
  for (int g = 0; g < 6; g++) {
    float4 v = rmax[prow][(c8 << 1) + g];
    r[4 * g + 0] = v.x; r[4 * g + 1] = v.y; r[4 * g + 2] = v.z; r[4 * g + 3] = v.w;
  }
  float core = r[8];
  #pragma unroll
  for (int k = 9; k <= 15; k++) core = fmaxf(core, r[k]);
  const float q7 = r[7];
  const float q6 = fmaxf(r[6], q7);
  const float q5 = fmaxf(r[5], q6);
  const float q4 = fmaxf(r[4], q5);
  const float q3 = fmaxf(r[3], q4);
  const float q2 = fmaxf(r[2], q3);
  const float q1 = fmaxf(r[1], q2);
  float sa[7];
  sa[0] = r[16];
  #pragma unroll
  for (int k = 1; k < 7; k++) sa[k] = fmaxf(sa[k - 1], r[16 + k]);
  float pooled[8];
  pooled[0] = fmaxf(core, q1);
  pooled[1] = fmaxf(fmaxf(core, q2), sa[0]);
  pooled[2] = fmaxf(fmaxf(core, q3), sa[1]);
  pooled[3] = fmaxf(fmaxf(core, q4), sa[2]);
  pooled[4] = fmaxf(fmaxf(core, q5), sa[3]);
  pooled[5] = fmaxf(fmaxf(core, q6), sa[4]);
  pooled[6] = fmaxf(fmaxf(core, q7), sa[5]);
  pooled[7] = fmaxf(core, sa[6]);

  const float4 cva = halo[prow + 7][(c8 << 1) + 2];   // raw score2 centers
  const float4 cvb = halo[prow + 7][(c8 << 1) + 3];
  const float cc[8] = {cva.x, cva.y, cva.z, cva.w, cvb.x, cvb.y, cvb.z, cvb.w};
  #pragma unroll
  for (int j = 0; j < 8; j++) {
    if ((mbits >> j) & 1u) {
      const float s = cc[j];
      if (s == pooled[j] && s > 0.f) {
        int slot = atomicAdd(&s_cnt, 1);            // LDS atomic, ~4/tile
        if (slot < BCAP) {
          s_cv[slot] = s;
          s_ci[slot] = (ty0 + prow) * W + tx0 + (c8 << 3) + j;
        }
      }
    }
  }
  // per-wave dense partials: plain global stores, no barrier needed
  #pragma unroll
  for (int off = 32; off > 0; off >>= 1) {
    t1 += __shfl_down(t1, off);
    mcnt += __shfl_down(mcnt, off);
  }
  if ((tid & 63) == 0) {
    ws->pt1[t * 4 + (tid >> 6)] = t1;
    ws->pmc[t * 4 + (tid >> 6)] = mcnt;
  }
  __syncthreads();
  // flush candidates + count (stored, not accumulated -> no pre-zero needed)
  int cnt = s_cnt; if (cnt > BCAP) cnt = BCAP;
  if (tid == 0) ws->tile_cnt[t] = cnt;
  if (tid < cnt) {
    ws->tile_val[t * BCAP + tid] = s_cv[tid];
    ws->tile_idx[t * BCAP + tid] = s_ci[tid];
  }
}

// One block per image: sum partials, scan tile counts, compact candidates,
// init corr, write rank-kernel float4 pad.
__global__ __launch_bounds__(256) void k_compact(WS* __restrict__ ws) {
  const int b = blockIdx.x;
  const int tid = threadIdx.x;
  const int lane = tid & 63, w = tid >> 6;
  __shared__ double sF[4];
  __shared__ int    sI[4];
  __shared__ int    wt[4];

  double tsum = 0.0; int msum = 0;
  for (int j = tid; j < 2048; j += 256) {
    tsum += (double)ws->pt1[b * 2048 + j];
    msum += ws->pmc[b * 2048 + j];
  }
  #pragma unroll
  for (int off = 32; off > 0; off >>= 1) {
    tsum += __shfl_down(tsum, off);
    msum += __shfl_down(msum, off);
  }
  if (lane == 0) { sF[w] = tsum; sI[w] = msum; }

  const int tg = b * 512 + 2 * tid;
  int c0 = ws->tile_cnt[tg];     if (c0 > BCAP) c0 = BCAP;
  int c1 = ws->tile_cnt[tg + 1]; if (c1 > BCAP) c1 = BCAP;
  const int pairs = c0 + c1;
  int v = pairs;
  #pragma unroll
  for (int off = 1; off < 64; off <<= 1) {
    int u = __shfl_up(v, off);
    if (lane >= off) v += u;
  }
  if (lane == 63) wt[w] = v;
  __syncthreads();
  if (tid == 0) {
    ws->term1[b] = (sF[0] + sF[1]) + (sF[2] + sF[3]);
    ws->masksum[b] = (unsigned int)(sI[0] + sI[1] + sI[2] + sI[3]);
    ws->corr[b] = 0.0;                       // replaces k_zero
  }
  int wo = 0;
  #pragma unroll
  for (int k = 0; k < 4; k++) if (k < w) wo += wt[k];
  const int excl = v - pairs + wo;
  float* dv = ws->ccand_val + b * CAP;
  int*   di = ws->ccand_idx + b * CAP;
  if (tid == 255) {
    int tot = excl + pairs;
    if (tot > CAP) tot = CAP;
    ws->cand_count[b] = tot;
    #pragma unroll
    for (int u = 0; u < 3; u++)              // float4 pad for rank kernel
      if (tot + u < CAP) dv[tot + u] = 0.f;
  }
  const float* sv0 = ws->tile_val + (size_t)tg * BCAP;
  const int*   si0 = ws->tile_idx + (size_t)tg * BCAP;
  for (int j = 0; j < c0; j++) {
    int o = excl + j;
    if (o < CAP) { dv[o] = sv0[j]; di[o] = si0[j]; }
  }
  for (int j = 0; j < c1; j++) {
    int o = excl + c0 + j;
    if (o < CAP) { dv[o] = sv0[BCAP + j]; di[o] = si0[BCAP + j]; }
  }
}

// Fused exact-rank + stamp: 64 cands/block, 4 waves split the j-scan 4-way.
__global__ __launch_bounds__(256, 4) void k_rankstamp(const float* __restrict__ score1,
                                                      const int* __restrict__ mask,
                                                      WS* __restrict__ ws) {
  // XCD swizzle: same-image blocks on same XCD (1024 = 8*128)
  const int blk = (blockIdx.x & 7) * 128 + (blockIdx.x >> 3);
  const int b = blk >> 6;
  const int slice = blk & 63;
  int n = ws->cand_count[b]; if (n > CAP) n = CAP;
  const int i0 = slice << 6;
  if (i0 >= n) return;
  __shared__ __align__(16) float sval[CAP];
  __shared__ __align__(16) int   sidx[CAP];
  __shared__ int   s_prank[4][64];
  __shared__ int   s_keys[64];
  __shared__ int   s_nk;
  __shared__ float cred[4];
  const int tid = threadIdx.x;
  const int nf4 = (n + 3) >> 2;

  const float4* gv = (const float4*)(ws->ccand_val + b * CAP);
  const int4*   gi = (const int4*)(ws->ccand_idx + b * CAP);
  for (int j = tid; j < nf4; j += 256) {
    ((float4*)sval)[j] = gv[j];
    ((int4*)sidx)[j]   = gi[j];
  }
  __syncthreads();

  const int w = tid >> 6, l = tid & 63;
  const float vi = sval[i0 + l];
  const int   xi = sidx[i0 + l];
  const int q = (nf4 + 3) >> 2;
  int lo = w * q; if (lo > nf4) lo = nf4;
  int hi = lo + q; if (hi > nf4) hi = nf4;
  int rank = 0;
  int j = lo;
  for (; j + 4 <= hi; j += 4) {
    #pragma unroll
    for (int u = 0; u < 4; u++) {
      const float4 v = ((const float4*)sval)[j + u];
      const int4  iv = ((const int4*)sidx)[j + u];
      rank += (v.x > vi) + (v.y > vi) + (v.z > vi) + (v.w > vi);
      rank += (v.x == vi && iv.x < xi);
      rank += (v.y == vi && iv.y < xi);
      rank += (v.z == vi && iv.z < xi);
      rank += (v.w == vi && iv.w < xi);
    }
  }
  for (; j < hi; j++) {
    const float4 v = ((const float4*)sval)[j];
    const int4  iv = ((const int4*)sidx)[j];
    rank += (v.x > vi) + (v.y > vi) + (v.z > vi) + (v.w > vi);
    rank += (v.x == vi && iv.x < xi);
    rank += (v.y == vi && iv.y < xi);
    rank += (v.z == vi && iv.z < xi);
    rank += (v.w == vi && iv.w < xi);
  }
  s_prank[w][l] = rank;
  __syncthreads();

  if (tid < 64) {
    const int rtot = s_prank[0][tid] + s_prank[1][tid] + s_prank[2][tid] + s_prank[3][tid];
    const bool sel = (i0 + tid < n) && (rtot < TOPK);
    const unsigned long long bal = __ballot(sel);
    if (sel) {
      const int pos = __popcll(bal & ((1ull << tid) - 1ull));
      s_keys[pos] = sidx[i0 + tid];
    }
    if (tid == 0) s_nk = (int)__popcll(bal);
  }
  __syncthreads();
  const int nk = s_nk;

  float contrib = 0.f;
  const int sub = tid & 7;
  const size_t ib2 = (size_t)b * ((size_t)H * W);
  #pragma unroll
  for (int rnd = 0; rnd < 2; rnd++) {
    const int k = (tid >> 3) + (rnd << 5);
    if (k < nk && sub < 7) {
      const int ck = s_keys[k];
      const int cy = ck >> 10, cx = ck & 1023;
      const int py = cy + sub - 3;
      const float wy = GW[sub] * ((py >= 0 && py < H) ? 1.f : 0.f);
      const int pyc = min(max(py, 0), H - 1);
      const float* s1r = score1 + ib2 + (size_t)pyc * W;
      const int*   mr  = mask   + ib2 + (size_t)pyc * W;
      #pragma unroll
      for (int dx = -3; dx <= 3; dx++) {
        const int px = cx + dx;
        const float wv = wy * GW[dx + 3] * ((px >= 0 && px < W) ? 1.f : 0.f);
        const int pxc = min(max(px, 0), W - 1);
        const float mf = (mr[pxc] != 0) ? 1.f : 0.f;
        contrib += mf * wv * (wv - 2.f * s1r[pxc]);
      }
    }
  }
  #pragma unroll
  for (int off = 32; off > 0; off >>= 1) contrib += __shfl_down(contrib, off);
  if ((tid & 63) == 0) cred[tid >> 6] = contrib;
  __syncthreads();
  if (tid == 0)
    atomicAdd(&ws->corr[b], (double)((cred[0] + cred[1]) + (cred[2] + cred[3])));
}

__global__ void k_final(WS* __restrict__ ws, float* __restrict__ out) {
  const int t = threadIdx.x;
  double v = 0.0;
  if (t < BATCH) {
    double denom = (double)ws->masksum[t];
    if (denom < 1e-8) denom = 1e-8;
    v = (ws->term1[t] + ws->corr[t]) / denom;
  }
  #pragma unroll
  for (int off = 32; off > 0; off >>= 1) v += __shfl_down(v, off);
  if (t == 0) out[0] = (float)(v / BATCH);
}

extern "C" void kernel_launch(void* const* d_in, const int* in_sizes, int n_in,
                              void* d_out, int out_size, void* d_ws, size_t ws_size,
                              hipStream_t stream) {
  const float* score1 = (const float*)d_in[0];
  const float* score2 = (const float*)d_in[1];
  const int*   mask   = (const int*)d_in[2];
  float* out = (float*)d_out;
  WS* ws = (WS*)d_ws;

  k_nms<<<NTILES, 256, 0, stream>>>(score1, score2, mask, ws);
  k_compact<<<BATCH, 256, 0, stream>>>(ws);
  k_rankstamp<<<BATCH * 64, 256, 0, stream>>>(score1, mask, ws);
  k_final<<<1, 64, 0, stream>>>(ws, out);
}